// Round 1
// baseline (1507.998 us; speedup 1.0000x reference)
//
#include <hip/hip_runtime.h>
#include <hip/hip_bf16.h>
#include <math.h>

#define B_ 2
#define S_ 2048
#define D_ 2048
#define H_ 16
#define DH_ 128
#define QP_ 1024
#define KVP_ 1365
#define RD_ 64
#define ND_ 64
#define FF_ 8192
#define T_ (B_*S_)          // 4096 tokens
#define CKW_ (KVP_+RD_)     // 1429
#define KVW_ 3072           // D + H*ND
#define KVP_PAD 1408        // 1365 -> mult of 64
#define CKW_PAD 1536        // 1429 -> mult of 128

typedef __attribute__((ext_vector_type(8))) short short8;
typedef __attribute__((ext_vector_type(4))) short sh4;
typedef __attribute__((ext_vector_type(4))) float floatx4;

__device__ __forceinline__ void gload_lds16(const __hip_bfloat16* g, __hip_bfloat16* l) {
    __builtin_amdgcn_global_load_lds((const __attribute__((address_space(1))) void*)g,
                                     (__attribute__((address_space(3))) void*)l, 16, 0, 0);
}
__device__ __forceinline__ short f2bs(float f) {
    __hip_bfloat16 h = __float2bfloat16(f);
    return *reinterpret_cast<short*>(&h);
}
// XOR-swizzled element offset into a [rows][64] bf16 LDS tile; g = 16B-group (0..7)
__device__ __forceinline__ int sw(int row, int g) { return row * 64 + ((g ^ (row & 7)) << 3); }

// fast gelu: 0.5*v*(1+erf(v/sqrt2)), A&S 7.1.26 erf approx (max err 1.5e-7)
__device__ __forceinline__ float fast_gelu(float v) {
    float x = v * 0.70710678118654752f;
    float ax = fabsf(x);
    float t = __builtin_amdgcn_rcpf(1.f + 0.3275911f * ax);
    float y = t * (0.254829592f + t * (-0.284496736f + t * (1.421413741f + t * (-1.453152027f + t * 1.061405429f))));
    float e = __expf(-ax * ax);
    float erfv = 1.f - y * e;
    erfv = copysignf(erfv, x);
    return 0.5f * v * (1.f + erfv);
}

// ---------------- LayerNorm -> bf16 out with zero-padded stride ----------------
__global__ __launch_bounds__(256) void ln_bf16(const float* __restrict__ in, int in_stride,
                                               const float* __restrict__ w, const float* __restrict__ bb,
                                               __hip_bfloat16* __restrict__ out, int out_stride, int N)
{
    int row = blockIdx.x;
    const float* ip = in + (size_t)row * in_stride;
    __hip_bfloat16* op = out + (size_t)row * out_stride;
    int tid = threadIdx.x;
    float sum = 0.f, sq = 0.f;
    for (int i = tid; i < N; i += 256) { float v = ip[i]; sum += v; sq += v * v; }
    __shared__ float s1[256], s2[256];
    s1[tid] = sum; s2[tid] = sq; __syncthreads();
    for (int s = 128; s > 0; s >>= 1) {
        if (tid < s) { s1[tid] += s1[tid + s]; s2[tid] += s2[tid + s]; }
        __syncthreads();
    }
    float mean = s1[0] / N;
    float var  = s2[0] / N - mean * mean;
    float rstd = rsqrtf(var + 1e-5f);
    for (int i = tid; i < N; i += 256) {
        float v = ip[i];
        op[i] = __float2bfloat16((v - mean) * rstd * w[i] + bb[i]);
    }
    for (int i = N + tid; i < out_stride; i += 256) op[i] = __float2bfloat16(0.f);
}

// ---------------- weight transpose + convert: W f32 [K,N] -> Wt bf16 [Npad,Kp] ----------------
__global__ __launch_bounds__(256) void transpose_cvt(const float* __restrict__ W, __hip_bfloat16* __restrict__ Wt,
                                                     int K, int N, int Kp)
{
    __shared__ float t[32][33];
    int k0 = blockIdx.x * 32, n0 = blockIdx.y * 32;
    int tx = threadIdx.x & 31, ty = threadIdx.x >> 5;
    for (int r = ty; r < 32; r += 8) {
        int k = k0 + r, n = n0 + tx;
        t[r][tx] = (k < K && n < N) ? W[(size_t)k * N + n] : 0.f;
    }
    __syncthreads();
    for (int r = ty; r < 32; r += 8) {
        int n = n0 + r, k = k0 + tx;
        Wt[(size_t)n * Kp + k] = __float2bfloat16(t[tx][r]);
    }
}

__global__ __launch_bounds__(256) void cvt_bf16(const float* __restrict__ in, __hip_bfloat16* __restrict__ out, int n)
{
    int i = blockIdx.x * 256 + threadIdx.x;
    if (i < n) out[i] = __float2bfloat16(in[i]);
}

// ---------------- bf16 MFMA GEMM (m97 structure + XOR-swizzled LDS) ----------------
// Kept for GEMMs whose 256^2 grid would be < 128 blocks (W_dq, W_dkv).
template<int EPI, typename CT>
__global__ __launch_bounds__(256) void gemm_bf16(const __hip_bfloat16* __restrict__ A,
                                                 const __hip_bfloat16* __restrict__ Bt,
                                                 CT* __restrict__ C, int M, int N, int Kp, int ldc,
                                                 const float* __restrict__ bias,
                                                 const float* __restrict__ resid)
{
    __shared__ __hip_bfloat16 As[128 * 64];
    __shared__ __hip_bfloat16 Bs[128 * 64];
    int tid = threadIdx.x;
    int bm = blockIdx.y * 128;
    int bn = blockIdx.x * 128;
    int wid = tid >> 6, lane = tid & 63;
    int wm = (wid >> 1) * 64, wn = (wid & 1) * 64;
    int lrow = lane & 15;
    int quad = lane >> 4;

    floatx4 acc[4][4];
    #pragma unroll
    for (int i = 0; i < 4; ++i)
        #pragma unroll
        for (int j = 0; j < 4; ++j)
            acc[i][j] = (floatx4){0.f, 0.f, 0.f, 0.f};

    for (int k0 = 0; k0 < Kp; k0 += 64) {
        #pragma unroll
        for (int it = 0; it < 4; ++it) {
            int chunk = it * 256 + tid;
            int row = chunk >> 3, g = chunk & 7;
            int col = (g ^ (row & 7)) << 3;
            gload_lds16(A + (size_t)(bm + row) * Kp + k0 + col, &As[chunk * 8]);
        }
        #pragma unroll
        for (int it = 0; it < 4; ++it) {
            int chunk = it * 256 + tid;
            int row = chunk >> 3, g = chunk & 7;
            int col = (g ^ (row & 7)) << 3;
            gload_lds16(Bt + (size_t)(bn + row) * Kp + k0 + col, &Bs[chunk * 8]);
        }
        __syncthreads();
        #pragma unroll
        for (int kk = 0; kk < 2; ++kk) {       // k-group s = kk*4 + quad
            short8 a[4], b[4];
            #pragma unroll
            for (int i = 0; i < 4; ++i)
                a[i] = *(const short8*)&As[sw(wm + i * 16 + lrow, kk * 4 + quad)];
            #pragma unroll
            for (int j = 0; j < 4; ++j)
                b[j] = *(const short8*)&Bs[sw(wn + j * 16 + lrow, kk * 4 + quad)];
            #pragma unroll
            for (int i = 0; i < 4; ++i)
                #pragma unroll
                for (int j = 0; j < 4; ++j)
                    acc[i][j] = __builtin_amdgcn_mfma_f32_16x16x32_bf16(a[i], b[j], acc[i][j], 0, 0, 0);
        }
        __syncthreads();
    }

    int cq4 = quad * 4;
    #pragma unroll
    for (int i = 0; i < 4; ++i) {
        #pragma unroll
        for (int j = 0; j < 4; ++j) {
            int col = bn + wn + j * 16 + lrow;
            if (col >= N) continue;
            #pragma unroll
            for (int r = 0; r < 4; ++r) {
                int rowg = bm + wm + i * 16 + cq4 + r;
                float v = acc[i][j][r];
                size_t idx = (size_t)rowg * ldc + col;
                if (EPI == 1) v += resid[idx];
                if (EPI == 2) { v += bias[col]; v = fast_gelu(v); }
                if (EPI == 3) { v += bias[col]; v += ((const float*)C)[idx]; }
                C[idx] = (CT)v;
            }
        }
    }
}

// ---------------- 256x256 8-phase bf16 MFMA GEMM (T1+T2+T3+T4+T5) ----------------
// 8 waves (2M x 4N), BK=64, 2 K-tiles/iter over 8 phases; one half-tile staged per
// phase (2 x global_load_lds dwordx4 per thread); counted vmcnt(4) gates ONLY at
// phases 3 and 7 (2 half-tiles always in flight); raw s_barrier (no vmcnt drain);
// setprio(1) around each 16-MFMA cluster. LDS 128 KiB, same 16B-group XOR swizzle
// as gemm_bf16 (linear DMA dest + pre-swizzled global source, rule #21).
// Schedule safety: every ds_read is first-used by the MFMA in its own phase (cannot
// sink); each LDS half-slot's last ds_read is >=1 barrier before its restage;
// first-read-after-gate ordering enforced by asm "memory" clobber + sched_barrier.
#define BAR8() __builtin_amdgcn_s_barrier()
#define SCB8() __builtin_amdgcn_sched_barrier(0)
#define GATE8(nw) asm volatile("s_waitcnt vmcnt(" #nw ")" ::: "memory")

template<int EPI, typename CT>
__global__ __launch_bounds__(512, 2) void gemm_8ph(const __hip_bfloat16* __restrict__ A,
                                                   const __hip_bfloat16* __restrict__ Bt,
                                                   CT* __restrict__ C, int M, int N, int Kp, int ldc,
                                                   const float* __restrict__ bias,
                                                   const float* __restrict__ resid)
{
    __shared__ __hip_bfloat16 As[2][16384];   // [buf][256 rows * 64]
    __shared__ __hip_bfloat16 Bs[2][16384];

    int tid = threadIdx.x;
    int wid = tid >> 6, lane = tid & 63;
    int lrow = lane & 15, quad = lane >> 4;
    int awm = (wid >> 2) * 128;               // warp_m in {0,1} -> 128-row half
    int bwn = (wid & 3) * 64;                 // warp_n in {0..3} -> 64-col quarter

    // bijective XCD-aware block swizzle (m204)
    int gx = gridDim.x;
    int nwg = gx * gridDim.y;
    int o = blockIdx.y * gx + blockIdx.x;
    int q8 = nwg >> 3, r8 = nwg & 7;
    int xcd = o & 7, oi = o >> 3;
    int s = (xcd < r8 ? xcd * (q8 + 1) : r8 * (q8 + 1) + (xcd - r8) * q8) + oi;
    int bm = (s / gx) * 256, bn = (s % gx) * 256;

    const __hip_bfloat16* Abm = A  + (size_t)bm * Kp;
    const __hip_bfloat16* Bbn = Bt + (size_t)bn * Kp;

    // staging pattern: per half-tile (128 rows x 64 cols) each thread does 2 loads.
    int drow = tid >> 3;                           // row 0..63 within a 64-row round
    int csw  = ((tid & 7) ^ (drow & 7)) << 3;      // pre-swizzled global k-offset
    int ldst = tid * 8;                            // linear LDS dest (elements)

#define STAGE8(srcbase, k0v, dst) do { \
    gload_lds16((srcbase) + (size_t)drow * Kp + (k0v) + csw, (dst) + ldst); \
    gload_lds16((srcbase) + (size_t)(drow + 64) * Kp + (k0v) + csw, (dst) + 4096 + ldst); \
  } while (0)

    // fragment read offsets: sw(row,g) with row&7 == lrow&7
    int abase = awm + lrow;
    int bbase = bwn + lrow;
    int k0off = ((quad       ^ (lrow & 7)) << 3);
    int k1off = (((4 + quad) ^ (lrow & 7)) << 3);

    short8 af[8][2], bfr[4][2];
    floatx4 acc[8][4];
    #pragma unroll
    for (int m = 0; m < 8; ++m)
        #pragma unroll
        for (int n = 0; n < 4; ++n)
            acc[m][n] = (floatx4){0.f, 0.f, 0.f, 0.f};

#define READ_A8(bufp, mh) do { \
    _Pragma("unroll") \
    for (int m = 0; m < 4; ++m) { \
      const __hip_bfloat16* p_ = (bufp) + (abase + ((mh)*4 + m) * 16) * 64; \
      af[(mh)*4 + m][0] = *(const short8*)(p_ + k0off); \
      af[(mh)*4 + m][1] = *(const short8*)(p_ + k1off); \
    } } while (0)

#define READ_B8(bufp, nh) do { \
    _Pragma("unroll") \
    for (int n = 0; n < 2; ++n) { \
      const __hip_bfloat16* p_ = (bufp) + (bbase + ((nh)*2 + n) * 16) * 64; \
      bfr[(nh)*2 + n][0] = *(const short8*)(p_ + k0off); \
      bfr[(nh)*2 + n][1] = *(const short8*)(p_ + k1off); \
    } } while (0)

#define QMFMA8(mh, nh) do { \
    __builtin_amdgcn_s_setprio(1); \
    _Pragma("unroll") \
    for (int kk = 0; kk < 2; ++kk) \
      _Pragma("unroll") \
      for (int m = 0; m < 4; ++m) \
        _Pragma("unroll") \
        for (int n = 0; n < 2; ++n) \
          acc[(mh)*4 + m][(nh)*2 + n] = __builtin_amdgcn_mfma_f32_16x16x32_bf16( \
              af[(mh)*4 + m][kk], bfr[(nh)*2 + n][kk], acc[(mh)*4 + m][(nh)*2 + n], 0, 0, 0); \
    __builtin_amdgcn_s_setprio(0); \
  } while (0)

    // prologue: tile0 {A0,A1,B0,B1} + tile1 {A0,A1}; wait tile0 (4 loads in flight)
    STAGE8(Abm,                   0,  &As[0][0]);
    STAGE8(Abm + (size_t)128*Kp,  0,  &As[0][8192]);
    STAGE8(Bbn,                   0,  &Bs[0][0]);
    STAGE8(Bbn + (size_t)128*Kp,  0,  &Bs[0][8192]);
    STAGE8(Abm,                   64, &As[1][0]);
    STAGE8(Abm + (size_t)128*Kp,  64, &As[1][8192]);
    GATE8(4); SCB8(); BAR8();

    int NT = Kp >> 6;
    #pragma unroll 1
    for (int t = 0; t < NT; t += 2) {
        int kn = (t + 1) << 6;
        int k2 = ((t + 2 < NT) ? t + 2 : NT - 1) << 6;   // tail clamp: staged but never read
        int k3 = ((t + 3 < NT) ? t + 3 : NT - 1) << 6;

        // ph0: stage B0(t+1); read A-half0 + B-quads01 of tile t; mfma (m0-3 x n0-1)
        STAGE8(Bbn, kn, &Bs[1][0]);
        READ_A8(&As[0][0], 0); READ_B8(&Bs[0][0], 0);
        SCB8(); BAR8();
        QMFMA8(0, 0);
        SCB8(); BAR8();
        // ph1: stage B1(t+1); read A-half1 + B-quads23; mfma (m4-7 x n2-3)
        STAGE8(Bbn + (size_t)128*Kp, kn, &Bs[1][8192]);
        READ_A8(&As[0][0], 1); READ_B8(&Bs[0][0], 1);
        SCB8(); BAR8();
        QMFMA8(1, 1);
        SCB8(); BAR8();
        // ph2: stage A0(t+2) over consumed As[0]; mfma (m0-3 x n2-3)
        STAGE8(Abm, k2, &As[0][0]);
        SCB8(); BAR8();
        QMFMA8(0, 1);
        SCB8(); BAR8();
        // ph3: stage A1(t+2); mfma (m4-7 x n0-1); GATE -> tile t+1 fully landed
        STAGE8(Abm + (size_t)128*Kp, k2, &As[0][8192]);
        SCB8(); BAR8();
        QMFMA8(1, 0);
        GATE8(4); SCB8(); BAR8();
        // ph4: stage B0(t+2); read tile t+1 A-half0 + B-quads01; mfma
        STAGE8(Bbn, k2, &Bs[0][0]);
        READ_A8(&As[1][0], 0); READ_B8(&Bs[1][0], 0);
        SCB8(); BAR8();
        QMFMA8(0, 0);
        SCB8(); BAR8();
        // ph5
        STAGE8(Bbn + (size_t)128*Kp, k2, &Bs[0][8192]);
        READ_A8(&As[1][0], 1); READ_B8(&Bs[1][0], 1);
        SCB8(); BAR8();
        QMFMA8(1, 1);
        SCB8(); BAR8();
        // ph6: stage A0(t+3)
        STAGE8(Abm, k3, &As[1][0]);
        SCB8(); BAR8();
        QMFMA8(0, 1);
        SCB8(); BAR8();
        // ph7: stage A1(t+3); GATE -> tile t+2 fully landed for next iteration
        STAGE8(Abm + (size_t)128*Kp, k3, &As[1][8192]);
        SCB8(); BAR8();
        QMFMA8(1, 0);
        GATE8(4); SCB8(); BAR8();
    }
    asm volatile("s_waitcnt vmcnt(0)" ::: "memory");

    int cq4 = quad * 4;
    #pragma unroll
    for (int m = 0; m < 8; ++m) {
        int rowg = bm + awm + m * 16 + cq4;
        #pragma unroll
        for (int n = 0; n < 4; ++n) {
            int col = bn + bwn + n * 16 + lrow;
            #pragma unroll
            for (int r = 0; r < 4; ++r) {
                float v = acc[m][n][r];
                size_t idx = (size_t)(rowg + r) * ldc + col;
                if (EPI == 1) v += resid[idx];
                if (EPI == 2) { v += bias[col]; v = fast_gelu(v); }
                if (EPI == 3) { v += bias[col]; v += ((const float*)C)[idx]; }
                C[idx] = (CT)v;
            }
        }
    }
#undef STAGE8
#undef READ_A8
#undef READ_B8
#undef QMFMA8
}

// ---------------- RoPE ----------------
__global__ __launch_bounds__(256) void rope_q_kernel(float* __restrict__ Q)
{
    int idx = blockIdx.x * 256 + threadIdx.x;        // T*H*32
    int i = idx & 31;
    int h = (idx >> 5) & (H_ - 1);
    int t = idx >> 9;
    float f = expf(-(float)i * (9.210340371976184f / 64.0f));
    float ang = (float)(t & (S_ - 1)) * f;
    float sv, cv; sincosf(ang, &sv, &cv);
    float* p = Q + (size_t)t * D_ + h * DH_ + ND_;
    float u = p[i], v = p[i + 32];
    p[i]      = u * cv - v * sv;
    p[i + 32] = v * cv + u * sv;
}

__global__ __launch_bounds__(256) void rope_kr_bf(const float* __restrict__ ckv, __hip_bfloat16* __restrict__ kr)
{
    int idx = blockIdx.x * 256 + threadIdx.x;        // T*32
    int i = idx & 31;
    int t = idx >> 5;
    float f = expf(-(float)i * (9.210340371976184f / 64.0f));
    float ang = (float)(t & (S_ - 1)) * f;
    float sv, cv; sincosf(ang, &sv, &cv);
    const float* src = ckv + (size_t)t * CKW_ + KVP_;
    float u = src[i], v = src[i + 32];
    kr[(size_t)t * RD_ + i]      = __float2bfloat16(u * cv - v * sv);
    kr[(size_t)t * RD_ + i + 32] = __float2bfloat16(v * cv + u * sv);
}

// ---------------- V transpose: kvu[t][h*192+64+v] -> Vt[b*H+h][v][t] (bf16) ----------------
__global__ __launch_bounds__(256) void vt_pack(const __hip_bfloat16* __restrict__ kvu,
                                               __hip_bfloat16* __restrict__ Vt)
{
    int bh = blockIdx.y; int b = bh >> 4, h = bh & 15;
    int v = threadIdx.x & 127;
    int tg = blockIdx.x * 2 + (threadIdx.x >> 7);
    int t0 = tg * 8;
    short8 o;
    #pragma unroll
    for (int j = 0; j < 8; ++j) {
        __hip_bfloat16 e = kvu[(size_t)(b * S_ + t0 + j) * KVW_ + h * 192 + 64 + v];
        o[j] = *reinterpret_cast<short*>(&e);
    }
    *(short8*)&Vt[((size_t)bh * 128 + v) * S_ + t0] = o;
}

// ---------------- Flash MFMA attention ----------------
__global__ __launch_bounds__(256) void attn_mfma(const float* __restrict__ Q,
                                                 const __hip_bfloat16* __restrict__ KVU,
                                                 const __hip_bfloat16* __restrict__ KR,
                                                 const __hip_bfloat16* __restrict__ VT,
                                                 __hip_bfloat16* __restrict__ O)
{
    __shared__ __hip_bfloat16 Kls[64 * 64];
    __shared__ __hip_bfloat16 Krls[64 * 64];
    __shared__ __hip_bfloat16 Vls[128 * 64];
    __shared__ __hip_bfloat16 Pls[4 * 32 * 64];

    int tid = threadIdx.x, wid = tid >> 6, lane = tid & 63;
    int lrow = lane & 15, quad = lane >> 4;
    int kq8 = quad * 8;
    int qtile = 15 - blockIdx.x;
    int bh = blockIdx.y, b = bh >> 4, h = bh & 15;
    int q0 = qtile * 128, wq = wid * 32;

    const float scale = 0.08838834764831845f;

    short8 bq[2][2], bqr[2][2];
    #pragma unroll
    for (int n = 0; n < 2; ++n) {
        const float* qrow = Q + (size_t)(b * S_ + q0 + wq + n * 16 + lrow) * D_ + h * DH_;
        #pragma unroll
        for (int s = 0; s < 2; ++s) {
            int base = s * 32 + kq8;
            #pragma unroll
            for (int j = 0; j < 8; ++j) {
                bq[n][s][j]  = f2bs(qrow[base + j] * scale);
                bqr[n][s][j] = f2bs(qrow[64 + base + j] * scale);
            }
        }
    }

    float mstate[2] = {-INFINITY, -INFINITY};
    float lstate[2] = {0.f, 0.f};
    floatx4 acco[8][2];
    #pragma unroll
    for (int vt = 0; vt < 8; ++vt)
        #pragma unroll
        for (int n = 0; n < 2; ++n)
            acco[vt][n] = (floatx4){0.f, 0.f, 0.f, 0.f};

    int nk = qtile * 2 + 2;
    int qmax_w = q0 + wq + 31;

    for (int kt = 0; kt < nk; ++kt) {
        int k0 = kt * 64;
        #pragma unroll
        for (int it = 0; it < 2; ++it) {
            int c = it * 256 + tid;
            int row = c >> 3, g = c & 7;
            int col = ((g ^ (row & 7)) << 3);
            gload_lds16(KVU + (size_t)(b * S_ + k0 + row) * KVW_ + h * 192 + col, &Kls[c * 8]);
            gload_lds16(KR + (size_t)(b * S_ + k0 + row) * RD_ + col, &Krls[c * 8]);
        }
        #pragma unroll
        for (int it = 0; it < 4; ++it) {
            int c = it * 256 + tid;
            int row = c >> 3, g = c & 7;
            int col = ((g ^ (row & 7)) << 3);
            gload_lds16(VT + ((size_t)bh * 128 + row) * S_ + k0 + col, &Vls[c * 8]);
        }
        __syncthreads();

        if (k0 <= qmax_w) {
            floatx4 sacc[4][2];
            #pragma unroll
            for (int m = 0; m < 4; ++m)
                #pragma unroll
                for (int n = 0; n < 2; ++n)
                    sacc[m][n] = (floatx4){0.f, 0.f, 0.f, 0.f};
            #pragma unroll
            for (int m = 0; m < 4; ++m) {
                short8 ak[2], akr[2];
                #pragma unroll
                for (int s = 0; s < 2; ++s) {
                    ak[s]  = *(const short8*)&Kls[sw(m * 16 + lrow, s * 4 + quad)];
                    akr[s] = *(const short8*)&Krls[sw(m * 16 + lrow, s * 4 + quad)];
                }
                #pragma unroll
                for (int n = 0; n < 2; ++n)
                    #pragma unroll
                    for (int s = 0; s < 2; ++s) {
                        sacc[m][n] = __builtin_amdgcn_mfma_f32_16x16x32_bf16(ak[s],  bq[n][s],  sacc[m][n], 0, 0, 0);
                        sacc[m][n] = __builtin_amdgcn_mfma_f32_16x16x32_bf16(akr[s], bqr[n][s], sacc[m][n], 0, 0, 0);
                    }
            }
            #pragma unroll
            for (int n = 0; n < 2; ++n) {
                int qg = q0 + wq + n * 16 + lrow;
                float tmax = -INFINITY;
                #pragma unroll
                for (int m = 0; m < 4; ++m)
                    #pragma unroll
                    for (int r = 0; r < 4; ++r) {
                        int kg = k0 + m * 16 + quad * 4 + r;
                        if (kg > qg) sacc[m][n][r] = -1e30f;
                        tmax = fmaxf(tmax, sacc[m][n][r]);
                    }
                tmax = fmaxf(tmax, __shfl_xor(tmax, 16));
                tmax = fmaxf(tmax, __shfl_xor(tmax, 32));
                float mnew = fmaxf(mstate[n], tmax);
                float alpha = __expf(mstate[n] - mnew);
                mstate[n] = mnew;
                float ps = 0.f;
                #pragma unroll
                for (int m = 0; m < 4; ++m) {
                    sh4 pk;
                    #pragma unroll
                    for (int r = 0; r < 4; ++r) {
                        float p = __expf(sacc[m][n][r] - mnew);
                        ps += p;
                        pk[r] = f2bs(p);
                    }
                    int qloc = n * 16 + lrow;
                    int off = wid * 2048 + qloc * 64 + (((m * 2 + (quad >> 1)) ^ (lrow & 7)) << 3) + ((quad & 1) << 2);
                    *(sh4*)&Pls[off] = pk;
                }
                ps += __shfl_xor(ps, 16);
                ps += __shfl_xor(ps, 32);
                lstate[n] = lstate[n] * alpha + ps;
                #pragma unroll
                for (int vt = 0; vt < 8; ++vt)
                    #pragma unroll
                    for (int r = 0; r < 4; ++r)
                        acco[vt][n][r] *= alpha;
            }
            short8 bp[2][2];
            #pragma unroll
            for (int n = 0; n < 2; ++n)
                #pragma unroll
                for (int s = 0; s < 2; ++s)
                    bp[n][s] = *(const short8*)&Pls[wid * 2048 + sw(n * 16 + lrow, s * 4 + quad)];
            #pragma unroll
            for (int vt = 0; vt < 8; ++vt) {
                short8 av[2];
                #pragma unroll
                for (int s = 0; s < 2; ++s)
                    av[s] = *(const short8*)&Vls[sw(vt * 16 + lrow, s * 4 + quad)];
                #pragma unroll
                for (int n = 0; n < 2; ++n)
                    #pragma unroll
                    for (int s = 0; s < 2; ++s)
                        acco[vt][n] = __builtin_amdgcn_mfma_f32_16x16x32_bf16(av[s], bp[n][s], acco[vt][n], 0, 0, 0);
            }
        }
        __syncthreads();
    }

    #pragma unroll
    for (int n = 0; n < 2; ++n) {
        float inv = 1.0f / lstate[n];
        int tok = b * S_ + q0 + wq + n * 16 + lrow;
        #pragma unroll
        for (int vt = 0; vt < 8; ++vt) {
            sh4 o4;
            #pragma unroll
            for (int r = 0; r < 4; ++r) o4[r] = f2bs(acco[vt][n][r] * inv);
            *(sh4*)&O[(size_t)tok * D_ + h * DH_ + vt * 16 + quad * 4] = o4;
        }
    }
}

// ---------------- Launcher ----------------
extern "C" void kernel_launch(void* const* d_in, const int* in_sizes, int n_in,
                              void* d_out, int out_size, void* d_ws, size_t ws_size,
                              hipStream_t stream)
{
    const float* x     = (const float*)d_in[0];
    const float* anw   = (const float*)d_in[1];
    const float* anb   = (const float*)d_in[2];
    const float* W_dq  = (const float*)d_in[3];
    const float* qlw   = (const float*)d_in[4];
    const float* qlb   = (const float*)d_in[5];
    const float* W_uq  = (const float*)d_in[6];
    const float* W_dkv = (const float*)d_in[7];
    const float* kvlw  = (const float*)d_in[8];
    const float* kvlb  = (const float*)d_in[9];
    const float* W_ukv = (const float*)d_in[10];
    const float* W_o   = (const float*)d_in[11];
    const float* fnw   = (const float*)d_in[12];
    const float* fnb   = (const float*)d_in[13];
    const float* W1    = (const float*)d_in[14];
    const float* b1    = (const float*)d_in[15];
    const float* W2    = (const float*)d_in[16];
    const float* b2    = (const float*)d_in[17];

    float* out0 = (float*)d_out;                     // [T, D]
    float* ckv  = out0 + (size_t)T_ * D_;            // [T, 1429]

    float* ws = (float*)d_ws;
    float* Q  = ws;                                          // [T,2048] f32
    float* cq = Q + (size_t)T_ * D_;                         // [T,1024] f32
    __hip_bfloat16* kvu_bf = (__hip_bfloat16*)(cq + (size_t)T_ * QP_);  // [T,3072]
    __hip_bfloat16* kr_bf  = kvu_bf + (size_t)T_ * KVW_;     // [T,64]
    __hip_bfloat16* Vt     = kr_bf + (size_t)T_ * RD_;       // [B*H][128][S]
    __hip_bfloat16* h_bf   = Vt + (size_t)T_ * D_;           // [T,2048]
    __hip_bfloat16* cq_bf  = h_bf + (size_t)T_ * D_;         // [T,1024]
    __hip_bfloat16* kvl_bf = cq_bf + (size_t)T_ * QP_;       // [T,1408]
    __hip_bfloat16* o_bf   = kvl_bf + (size_t)T_ * KVP_PAD;  // [T,2048]
    __hip_bfloat16* wdq_t  = o_bf + (size_t)T_ * D_;         // [1024,2048]
    __hip_bfloat16* wuq_t  = wdq_t + (size_t)QP_ * D_;       // [2048,1024]
    __hip_bfloat16* wdkv_t = wuq_t + (size_t)D_ * QP_;       // [1536,2048]
    __hip_bfloat16* wukv_t = wdkv_t + (size_t)CKW_PAD * D_;  // [3072,1408]
    __hip_bfloat16* wo_b   = wukv_t + (size_t)KVW_ * KVP_PAD;// [2048,2048]
    __hip_bfloat16* w1_t   = wo_b + (size_t)D_ * D_;         // [8192,2048]
    __hip_bfloat16* w2_t   = w1_t + (size_t)FF_ * D_;        // [2048,8192]
    __hip_bfloat16* ff1_bf = (__hip_bfloat16*)ws;            // overlays Q+cq+kvu (dead by FFN)

    dim3 blk(256);
    dim3 blk8(512);

    { dim3 g(D_ / 32, QP_ / 32);       transpose_cvt<<<g, blk, 0, stream>>>(W_dq,  wdq_t,  D_, QP_, D_); }
    { dim3 g(QP_ / 32, D_ / 32);       transpose_cvt<<<g, blk, 0, stream>>>(W_uq,  wuq_t,  QP_, D_, QP_); }
    { dim3 g(D_ / 32, CKW_PAD / 32);   transpose_cvt<<<g, blk, 0, stream>>>(W_dkv, wdkv_t, D_, CKW_, D_); }
    { dim3 g(KVP_PAD / 32, KVW_ / 32); transpose_cvt<<<g, blk, 0, stream>>>(W_ukv, wukv_t, KVP_, KVW_, KVP_PAD); }
    { int n = D_ * D_;                 cvt_bf16<<<(n + 255) / 256, blk, 0, stream>>>(W_o, wo_b, n); }
    { dim3 g(D_ / 32, FF_ / 32);       transpose_cvt<<<g, blk, 0, stream>>>(W1, w1_t, D_, FF_, D_); }
    { dim3 g(FF_ / 32, D_ / 32);       transpose_cvt<<<g, blk, 0, stream>>>(W2, w2_t, FF_, D_, FF_); }

    ln_bf16<<<T_, blk, 0, stream>>>(x, D_, anw, anb, h_bf, D_, D_);
    { dim3 g(QP_ / 128, T_ / 128);   // 256-grid would be 64 blocks at 256^2 -> keep 128^2
      gemm_bf16<0, float><<<g, blk, 0, stream>>>(h_bf, wdq_t, cq, T_, QP_, D_, QP_, nullptr, nullptr); }
    ln_bf16<<<T_, blk, 0, stream>>>(cq, QP_, qlw, qlb, cq_bf, QP_, QP_);
    { dim3 g(D_ / 256, T_ / 256);
      gemm_8ph<0, float><<<g, blk8, 0, stream>>>(cq_bf, wuq_t, Q, T_, D_, QP_, D_, nullptr, nullptr); }
    rope_q_kernel<<<(T_ * H_ * 32) / 256, blk, 0, stream>>>(Q);
    { dim3 g(CKW_PAD / 128, T_ / 128);  // 96 blocks at 256^2 -> keep 128^2
      gemm_bf16<0, float><<<g, blk, 0, stream>>>(h_bf, wdkv_t, ckv, T_, CKW_, D_, CKW_, nullptr, nullptr); }
    ln_bf16<<<T_, blk, 0, stream>>>(ckv, CKW_, kvlw, kvlb, kvl_bf, KVP_PAD, KVP_);
    { dim3 g(KVW_ / 256, T_ / 256);
      gemm_8ph<0, __hip_bfloat16><<<g, blk8, 0, stream>>>(kvl_bf, wukv_t, kvu_bf, T_, KVW_, KVP_PAD, KVW_, nullptr, nullptr); }
    rope_kr_bf<<<(T_ * 32) / 256, blk, 0, stream>>>(ckv, kr_bf);
    { dim3 g(S_ / 16, B_ * H_);
      vt_pack<<<g, blk, 0, stream>>>(kvu_bf, Vt); }
    { dim3 g(16, B_ * H_);
      attn_mfma<<<g, blk, 0, stream>>>(Q, kvu_bf, kr_bf, Vt, o_bf); }
    { dim3 g(D_ / 256, T_ / 256);
      gemm_8ph<1, float><<<g, blk8, 0, stream>>>(o_bf, wo_b, out0, T_, D_, D_, D_, nullptr, x); }
    ln_bf16<<<T_, blk, 0, stream>>>(out0, D_, fnw, fnb, h_bf, D_, D_);
    { dim3 g(FF_ / 256, T_ / 256);
      gemm_8ph<2, __hip_bfloat16><<<g, blk8, 0, stream>>>(h_bf, w1_t, ff1_bf, T_, FF_, D_, FF_, b1, nullptr); }
    { dim3 g(D_ / 256, T_ / 256);
      gemm_8ph<3, float><<<g, blk8, 0, stream>>>(ff1_bf, w2_t, out0, T_, D_, FF_, D_, b2, nullptr); }
}

// Round 2
// 1070.410 us; speedup vs baseline: 1.4088x; 1.4088x over previous
//
#include <hip/hip_runtime.h>
#include <hip/hip_bf16.h>
#include <math.h>

#define B_ 2
#define S_ 2048
#define D_ 2048
#define H_ 16
#define DH_ 128
#define QP_ 1024
#define KVP_ 1365
#define RD_ 64
#define ND_ 64
#define FF_ 8192
#define T_ (B_*S_)          // 4096 tokens
#define CKW_ (KVP_+RD_)     // 1429
#define KVW_ 3072           // D + H*ND
#define KVP_PAD 1408        // 1365 -> mult of 64
#define CKW_PAD 1536        // 1429 -> mult of 128

typedef __attribute__((ext_vector_type(8))) short short8;
typedef __attribute__((ext_vector_type(4))) short sh4;
typedef __attribute__((ext_vector_type(4))) float floatx4;

__device__ __forceinline__ void gload_lds16(const __hip_bfloat16* g, __hip_bfloat16* l) {
    __builtin_amdgcn_global_load_lds((const __attribute__((address_space(1))) void*)g,
                                     (__attribute__((address_space(3))) void*)l, 16, 0, 0);
}
__device__ __forceinline__ short f2bs(float f) {
    __hip_bfloat16 h = __float2bfloat16(f);
    return *reinterpret_cast<short*>(&h);
}
// XOR-swizzled element offset into a [rows][64] bf16 LDS tile; g = 16B-group (0..7)
__device__ __forceinline__ int sw(int row, int g) { return row * 64 + ((g ^ (row & 7)) << 3); }

// fast gelu: 0.5*v*(1+erf(v/sqrt2)), A&S 7.1.26 erf approx (max err 1.5e-7)
__device__ __forceinline__ float fast_gelu(float v) {
    float x = v * 0.70710678118654752f;
    float ax = fabsf(x);
    float t = __builtin_amdgcn_rcpf(1.f + 0.3275911f * ax);
    float y = t * (0.254829592f + t * (-0.284496736f + t * (1.421413741f + t * (-1.453152027f + t * 1.061405429f))));
    float e = __expf(-ax * ax);
    float erfv = 1.f - y * e;
    erfv = copysignf(erfv, x);
    return 0.5f * v * (1.f + erfv);
}

// ---------------- LayerNorm -> bf16 out with zero-padded stride ----------------
__global__ __launch_bounds__(256) void ln_bf16(const float* __restrict__ in, int in_stride,
                                               const float* __restrict__ w, const float* __restrict__ bb,
                                               __hip_bfloat16* __restrict__ out, int out_stride, int N)
{
    int row = blockIdx.x;
    const float* ip = in + (size_t)row * in_stride;
    __hip_bfloat16* op = out + (size_t)row * out_stride;
    int tid = threadIdx.x;
    __shared__ float s1[256], s2[256];
    float sum = 0.f, sq = 0.f;
    bool vec = (((in_stride | N | out_stride) & 3) == 0);   // block-uniform
    if (vec) {
        const float4* ip4 = (const float4*)ip;
        int n4 = N >> 2;
        for (int i = tid; i < n4; i += 256) {
            float4 v = ip4[i];
            sum += v.x + v.y + v.z + v.w;
            sq  += v.x * v.x + v.y * v.y + v.z * v.z + v.w * v.w;
        }
        s1[tid] = sum; s2[tid] = sq; __syncthreads();
        for (int s = 128; s > 0; s >>= 1) {
            if (tid < s) { s1[tid] += s1[tid + s]; s2[tid] += s2[tid + s]; }
            __syncthreads();
        }
        float mean = s1[0] / N;
        float var  = s2[0] / N - mean * mean;
        float rstd = rsqrtf(var + 1e-5f);
        const float4* w4 = (const float4*)w;
        const float4* b4 = (const float4*)bb;
        for (int i = tid; i < n4; i += 256) {
            float4 v = ip4[i], wv = w4[i], bv = b4[i];
            sh4 o;
            o[0] = f2bs((v.x - mean) * rstd * wv.x + bv.x);
            o[1] = f2bs((v.y - mean) * rstd * wv.y + bv.y);
            o[2] = f2bs((v.z - mean) * rstd * wv.z + bv.z);
            o[3] = f2bs((v.w - mean) * rstd * wv.w + bv.w);
            *(sh4*)&op[i * 4] = o;
        }
    } else {
        for (int i = tid; i < N; i += 256) { float v = ip[i]; sum += v; sq += v * v; }
        s1[tid] = sum; s2[tid] = sq; __syncthreads();
        for (int s = 128; s > 0; s >>= 1) {
            if (tid < s) { s1[tid] += s1[tid + s]; s2[tid] += s2[tid + s]; }
            __syncthreads();
        }
        float mean = s1[0] / N;
        float var  = s2[0] / N - mean * mean;
        float rstd = rsqrtf(var + 1e-5f);
        for (int i = tid; i < N; i += 256) {
            float v = ip[i];
            op[i] = __float2bfloat16((v - mean) * rstd * w[i] + bb[i]);
        }
    }
    for (int i = N + tid; i < out_stride; i += 256) op[i] = __float2bfloat16(0.f);
}

// ---------------- weight transpose + convert: W f32 [K,N] -> Wt bf16 [Npad,Kp] ----------------
__global__ __launch_bounds__(256) void transpose_cvt(const float* __restrict__ W, __hip_bfloat16* __restrict__ Wt,
                                                     int K, int N, int Kp)
{
    __shared__ float t[32][33];
    int k0 = blockIdx.x * 32, n0 = blockIdx.y * 32;
    int tx = threadIdx.x & 31, ty = threadIdx.x >> 5;
    for (int r = ty; r < 32; r += 8) {
        int k = k0 + r, n = n0 + tx;
        t[r][tx] = (k < K && n < N) ? W[(size_t)k * N + n] : 0.f;
    }
    __syncthreads();
    for (int r = ty; r < 32; r += 8) {
        int n = n0 + r, k = k0 + tx;
        Wt[(size_t)n * Kp + k] = __float2bfloat16(t[tx][r]);
    }
}

__global__ __launch_bounds__(256) void cvt_bf16(const float* __restrict__ in, __hip_bfloat16* __restrict__ out, int n)
{
    int i = blockIdx.x * 256 + threadIdx.x;
    if (i < n) out[i] = __float2bfloat16(in[i]);
}

// ---------------- bf16 MFMA GEMM (m97 structure + XOR-swizzled LDS + XCD swizzle) ----------------
template<int EPI, typename CT>
__global__ __launch_bounds__(256) void gemm_bf16(const __hip_bfloat16* __restrict__ A,
                                                 const __hip_bfloat16* __restrict__ Bt,
                                                 CT* __restrict__ C, int M, int N, int Kp, int ldc,
                                                 const float* __restrict__ bias,
                                                 const float* __restrict__ resid)
{
    __shared__ __hip_bfloat16 As[128 * 64];
    __shared__ __hip_bfloat16 Bs[128 * 64];
    int tid = threadIdx.x;
    // XCD chunk swizzle (T1): consecutive slots on one XCD share bm -> A-panel L2 reuse
    int gx = gridDim.x;
    int nwg = gx * gridDim.y;
    int o = blockIdx.y * gx + blockIdx.x;
    int sId = ((nwg & 7) == 0) ? ((o & 7) * (nwg >> 3) + (o >> 3)) : o;
    int bm = (sId / gx) * 128;
    int bn = (sId % gx) * 128;
    int wid = tid >> 6, lane = tid & 63;
    int wm = (wid >> 1) * 64, wn = (wid & 1) * 64;
    int lrow = lane & 15;
    int quad = lane >> 4;

    floatx4 acc[4][4];
    #pragma unroll
    for (int i = 0; i < 4; ++i)
        #pragma unroll
        for (int j = 0; j < 4; ++j)
            acc[i][j] = (floatx4){0.f, 0.f, 0.f, 0.f};

    for (int k0 = 0; k0 < Kp; k0 += 64) {
        #pragma unroll
        for (int it = 0; it < 4; ++it) {
            int chunk = it * 256 + tid;
            int row = chunk >> 3, g = chunk & 7;
            int col = (g ^ (row & 7)) << 3;
            gload_lds16(A + (size_t)(bm + row) * Kp + k0 + col, &As[chunk * 8]);
        }
        #pragma unroll
        for (int it = 0; it < 4; ++it) {
            int chunk = it * 256 + tid;
            int row = chunk >> 3, g = chunk & 7;
            int col = (g ^ (row & 7)) << 3;
            gload_lds16(Bt + (size_t)(bn + row) * Kp + k0 + col, &Bs[chunk * 8]);
        }
        __syncthreads();
        #pragma unroll
        for (int kk = 0; kk < 2; ++kk) {       // k-group s = kk*4 + quad
            short8 a[4], b[4];
            #pragma unroll
            for (int i = 0; i < 4; ++i)
                a[i] = *(const short8*)&As[sw(wm + i * 16 + lrow, kk * 4 + quad)];
            #pragma unroll
            for (int j = 0; j < 4; ++j)
                b[j] = *(const short8*)&Bs[sw(wn + j * 16 + lrow, kk * 4 + quad)];
            #pragma unroll
            for (int i = 0; i < 4; ++i)
                #pragma unroll
                for (int j = 0; j < 4; ++j)
                    acc[i][j] = __builtin_amdgcn_mfma_f32_16x16x32_bf16(a[i], b[j], acc[i][j], 0, 0, 0);
        }
        __syncthreads();
    }

    int cq4 = quad * 4;
    #pragma unroll
    for (int i = 0; i < 4; ++i) {
        #pragma unroll
        for (int j = 0; j < 4; ++j) {
            int col = bn + wn + j * 16 + lrow;
            if (col >= N) continue;
            #pragma unroll
            for (int r = 0; r < 4; ++r) {
                int rowg = bm + wm + i * 16 + cq4 + r;
                float v = acc[i][j][r];
                size_t idx = (size_t)rowg * ldc + col;
                if (EPI == 1) v += resid[idx];
                if (EPI == 2) { v += bias[col]; v = fast_gelu(v); }
                if (EPI == 3) { v += bias[col]; v += ((const float*)C)[idx]; }
                C[idx] = (CT)v;
            }
        }
    }
}

// ---------------- 256x256 8-phase bf16 MFMA GEMM (T1+T2+T3+T4+T5) ----------------
// launch_bounds(512,1): 1 block/CU -> 256-VGPR/wave budget. Round-1 failure was
// (512,2) -> 128-reg budget -> acc[8][4] alone = 128 regs -> total spill to scratch.
// Phase layout (per K-tile, 4 phases): stages {B0',B1',-,A0''+A1''}, reads spread
// 12/4/8/0, every LDS region's last read >=1 barrier before its restage:
//   As[x] read ph0 (mh0) + ph2 (mh1), restaged ph3 (both halves)  -> safe
//   Bs[x] read ph0/ph1, restaged next half-iteration ph0/ph1      -> safe
// Counted vmcnt(4) at ph3/ph7 only: completes tile t+1 (A staged prev iter ph7,
// B staged ph0/ph1), leaves next tile's 4 A-loads in flight across the boundary.
#define BAR8() __builtin_amdgcn_s_barrier()
#define SCB8() __builtin_amdgcn_sched_barrier(0)
#define GATE8(nw) asm volatile("s_waitcnt vmcnt(" #nw ")" ::: "memory")

template<int EPI, typename CT>
__global__ __launch_bounds__(512, 1) void gemm_8ph(const __hip_bfloat16* __restrict__ A,
                                                   const __hip_bfloat16* __restrict__ Bt,
                                                   CT* __restrict__ C, int M, int N, int Kp, int ldc,
                                                   const float* __restrict__ bias,
                                                   const float* __restrict__ resid)
{
    __shared__ __hip_bfloat16 As[2][16384];   // [buf][256 rows * 64]
    __shared__ __hip_bfloat16 Bs[2][16384];

    int tid = threadIdx.x;
    int wid = tid >> 6, lane = tid & 63;
    int lrow = lane & 15, quad = lane >> 4;
    int awm = (wid >> 2) * 128;               // warp_m in {0,1} -> 128-row half
    int bwn = (wid & 3) * 64;                 // warp_n in {0..3} -> 64-col quarter

    // bijective XCD-aware block swizzle (m204)
    int gx = gridDim.x;
    int nwg = gx * gridDim.y;
    int o = blockIdx.y * gx + blockIdx.x;
    int q8 = nwg >> 3, r8 = nwg & 7;
    int xcd = o & 7, oi = o >> 3;
    int s = (xcd < r8 ? xcd * (q8 + 1) : r8 * (q8 + 1) + (xcd - r8) * q8) + oi;
    int bm = (s / gx) * 256, bn = (s % gx) * 256;

    const __hip_bfloat16* Abm = A  + (size_t)bm * Kp;
    const __hip_bfloat16* Bbn = Bt + (size_t)bn * Kp;

    // staging: per half-tile (128 rows x 64 cols) each thread does 2 loads (16B each)
    int drow = tid >> 3;                           // row 0..63 within a 64-row round
    int csw  = ((tid & 7) ^ (drow & 7)) << 3;      // pre-swizzled global k-offset
    int ldst = tid * 8;                            // linear LDS dest (elements)

#define STAGE8(srcbase, k0v, dst) do { \
    gload_lds16((srcbase) + (size_t)drow * Kp + (k0v) + csw, (dst) + ldst); \
    gload_lds16((srcbase) + (size_t)(drow + 64) * Kp + (k0v) + csw, (dst) + 4096 + ldst); \
  } while (0)

    int abase = awm + lrow;
    int bbase = bwn + lrow;
    int k0off = ((quad       ^ (lrow & 7)) << 3);
    int k1off = (((4 + quad) ^ (lrow & 7)) << 3);

    short8 af[8][2], bfr[4][2];
    floatx4 acc[8][4];
    #pragma unroll
    for (int m = 0; m < 8; ++m)
        #pragma unroll
        for (int n = 0; n < 4; ++n)
            acc[m][n] = (floatx4){0.f, 0.f, 0.f, 0.f};

#define READ_A8(bufp, mh) do { \
    _Pragma("unroll") \
    for (int m = 0; m < 4; ++m) { \
      const __hip_bfloat16* p_ = (bufp) + (abase + ((mh)*4 + m) * 16) * 64; \
      af[(mh)*4 + m][0] = *(const short8*)(p_ + k0off); \
      af[(mh)*4 + m][1] = *(const short8*)(p_ + k1off); \
    } } while (0)

#define READ_B8(bufp, nh) do { \
    _Pragma("unroll") \
    for (int n = 0; n < 2; ++n) { \
      const __hip_bfloat16* p_ = (bufp) + (bbase + ((nh)*2 + n) * 16) * 64; \
      bfr[(nh)*2 + n][0] = *(const short8*)(p_ + k0off); \
      bfr[(nh)*2 + n][1] = *(const short8*)(p_ + k1off); \
    } } while (0)

#define QMFMA8(mh, nh) do { \
    __builtin_amdgcn_s_setprio(1); \
    _Pragma("unroll") \
    for (int kk = 0; kk < 2; ++kk) \
      _Pragma("unroll") \
      for (int m = 0; m < 4; ++m) \
        _Pragma("unroll") \
        for (int n = 0; n < 2; ++n) \
          acc[(mh)*4 + m][(nh)*2 + n] = __builtin_amdgcn_mfma_f32_16x16x32_bf16( \
              af[(mh)*4 + m][kk], bfr[(nh)*2 + n][kk], acc[(mh)*4 + m][(nh)*2 + n], 0, 0, 0); \
    __builtin_amdgcn_s_setprio(0); \
  } while (0)

    // prologue: tile0 {A0,A1,B0,B1} + tile1 {A0,A1}; GATE(4) -> tile0 landed,
    // tile1's 4 A-loads stay in flight (loop invariant at iteration entry)
    STAGE8(Abm,                   0,  &As[0][0]);
    STAGE8(Abm + (size_t)128*Kp,  0,  &As[0][8192]);
    STAGE8(Bbn,                   0,  &Bs[0][0]);
    STAGE8(Bbn + (size_t)128*Kp,  0,  &Bs[0][8192]);
    STAGE8(Abm,                   64, &As[1][0]);
    STAGE8(Abm + (size_t)128*Kp,  64, &As[1][8192]);
    GATE8(4); SCB8(); BAR8();

    int NT = Kp >> 6;
    #pragma unroll 1
    for (int t = 0; t < NT; t += 2) {
        int kn = (t + 1) << 6;
        int k2 = ((t + 2 < NT) ? t + 2 : NT - 1) << 6;   // tail clamp: staged, never read
        int k3 = ((t + 3 < NT) ? t + 3 : NT - 1) << 6;

        // ph0: stage B0(t+1); read A-mh0 + B-lo of tile t; mfma (m0-3 x n-lo)
        STAGE8(Bbn, kn, &Bs[1][0]);
        READ_A8(&As[0][0], 0); READ_B8(&Bs[0][0], 0);
        SCB8(); BAR8();
        QMFMA8(0, 0);
        SCB8(); BAR8();
        // ph1: stage B1(t+1); read B-hi; mfma (m0-3 x n-hi)
        STAGE8(Bbn + (size_t)128*Kp, kn, &Bs[1][8192]);
        READ_B8(&Bs[0][0], 1);
        SCB8(); BAR8();
        QMFMA8(0, 1);
        SCB8(); BAR8();
        // ph2: read A-mh1; mfma (m4-7 x n-hi)
        READ_A8(&As[0][0], 1);
        SCB8(); BAR8();
        QMFMA8(1, 1);
        SCB8(); BAR8();
        // ph3: stage A(t+2) both halves (As[0] fully read by ph2); mfma (m4-7 x n-lo);
        //      GATE(4): tile t+1 (A from prev ph7, B from ph0/ph1) fully landed
        STAGE8(Abm, k2, &As[0][0]);
        STAGE8(Abm + (size_t)128*Kp, k2, &As[0][8192]);
        SCB8(); BAR8();
        QMFMA8(1, 0);
        GATE8(4); SCB8(); BAR8();
        // ph4-ph7: tile t+1 from As[1]/Bs[1]; stage B(t+2)->Bs[0], A(t+3)->As[1]
        STAGE8(Bbn, k2, &Bs[0][0]);
        READ_A8(&As[1][0], 0); READ_B8(&Bs[1][0], 0);
        SCB8(); BAR8();
        QMFMA8(0, 0);
        SCB8(); BAR8();
        // ph5
        STAGE8(Bbn + (size_t)128*Kp, k2, &Bs[0][8192]);
        READ_B8(&Bs[1][0], 1);
        SCB8(); BAR8();
        QMFMA8(0, 1);
        SCB8(); BAR8();
        // ph6
        READ_A8(&As[1][0], 1);
        SCB8(); BAR8();
        QMFMA8(1, 1);
        SCB8(); BAR8();
        // ph7
        STAGE8(Abm, k3, &As[1][0]);
        STAGE8(Abm + (size_t)128*Kp, k3, &As[1][8192]);
        SCB8(); BAR8();
        QMFMA8(1, 0);
        GATE8(4); SCB8(); BAR8();
    }
    asm volatile("s_waitcnt vmcnt(0)" ::: "memory");

    int cq4 = quad * 4;
    #pragma unroll
    for (int m = 0; m < 8; ++m) {
        int rowg = bm + awm + m * 16 + cq4;
        #pragma unroll
        for (int n = 0; n < 4; ++n) {
            int col = bn + bwn + n * 16 + lrow;
            #pragma unroll
            for (int r = 0; r < 4; ++r) {
                float v = acc[m][n][r];
                size_t idx = (size_t)(rowg + r) * ldc + col;
                if (EPI == 1) v += resid[idx];
                if (EPI == 2) { v += bias[col]; v = fast_gelu(v); }
                if (EPI == 3) { v += bias[col]; v += ((const float*)C)[idx]; }
                C[idx] = (CT)v;
            }
        }
    }
#undef STAGE8
#undef READ_A8
#undef READ_B8
#undef QMFMA8
}

// ---------------- RoPE ----------------
__global__ __launch_bounds__(256) void rope_q_kernel(float* __restrict__ Q)
{
    int idx = blockIdx.x * 256 + threadIdx.x;        // T*H*32
    int i = idx & 31;
    int h = (idx >> 5) & (H_ - 1);
    int t = idx >> 9;
    float f = expf(-(float)i * (9.210340371976184f / 64.0f));
    float ang = (float)(t & (S_ - 1)) * f;
    float sv, cv; sincosf(ang, &sv, &cv);
    float* p = Q + (size_t)t * D_ + h * DH_ + ND_;
    float u = p[i], v = p[i + 32];
    p[i]      = u * cv - v * sv;
    p[i + 32] = v * cv + u * sv;
}

__global__ __launch_bounds__(256) void rope_kr_bf(const float* __restrict__ ckv, __hip_bfloat16* __restrict__ kr)
{
    int idx = blockIdx.x * 256 + threadIdx.x;        // T*32
    int i = idx & 31;
    int t = idx >> 5;
    float f = expf(-(float)i * (9.210340371976184f / 64.0f));
    float ang = (float)(t & (S_ - 1)) * f;
    float sv, cv; sincosf(ang, &sv, &cv);
    const float* src = ckv + (size_t)t * CKW_ + KVP_;
    float u = src[i], v = src[i + 32];
    kr[(size_t)t * RD_ + i]      = __float2bfloat16(u * cv - v * sv);
    kr[(size_t)t * RD_ + i + 32] = __float2bfloat16(v * cv + u * sv);
}

// ---------------- V transpose: kvu[t][h*192+64+v] -> Vt[b*H+h][v][t] (bf16) ----------------
__global__ __launch_bounds__(256) void vt_pack(const __hip_bfloat16* __restrict__ kvu,
                                               __hip_bfloat16* __restrict__ Vt)
{
    int bh = blockIdx.y; int b = bh >> 4, h = bh & 15;
    int v = threadIdx.x & 127;
    int tg = blockIdx.x * 2 + (threadIdx.x >> 7);
    int t0 = tg * 8;
    short8 o;
    #pragma unroll
    for (int j = 0; j < 8; ++j) {
        __hip_bfloat16 e = kvu[(size_t)(b * S_ + t0 + j) * KVW_ + h * 192 + 64 + v];
        o[j] = *reinterpret_cast<short*>(&e);
    }
    *(short8*)&Vt[((size_t)bh * 128 + v) * S_ + t0] = o;
}

// ---------------- Flash MFMA attention (+ XCD chunk swizzle: same bh -> same XCD) ----
__global__ __launch_bounds__(256) void attn_mfma(const float* __restrict__ Q,
                                                 const __hip_bfloat16* __restrict__ KVU,
                                                 const __hip_bfloat16* __restrict__ KR,
                                                 const __hip_bfloat16* __restrict__ VT,
                                                 __hip_bfloat16* __restrict__ O)
{
    __shared__ __hip_bfloat16 Kls[64 * 64];
    __shared__ __hip_bfloat16 Krls[64 * 64];
    __shared__ __hip_bfloat16 Vls[128 * 64];
    __shared__ __hip_bfloat16 Pls[4 * 32 * 64];

    int tid = threadIdx.x, wid = tid >> 6, lane = tid & 63;
    int lrow = lane & 15, quad = lane >> 4;
    int kq8 = quad * 8;
    // chunk swizzle: nwg = 512 (16 x 32); XCD k gets 4 consecutive bh values
    int o = blockIdx.y * 16 + blockIdx.x;
    int sId = (o & 7) * 64 + (o >> 3);
    int qtile = 15 - (sId & 15);
    int bh = sId >> 4;
    int b = bh >> 4, h = bh & 15;
    int q0 = qtile * 128, wq = wid * 32;

    const float scale = 0.08838834764831845f;

    short8 bq[2][2], bqr[2][2];
    #pragma unroll
    for (int n = 0; n < 2; ++n) {
        const float* qrow = Q + (size_t)(b * S_ + q0 + wq + n * 16 + lrow) * D_ + h * DH_;
        #pragma unroll
        for (int s = 0; s < 2; ++s) {
            int base = s * 32 + kq8;
            #pragma unroll
            for (int j = 0; j < 8; ++j) {
                bq[n][s][j]  = f2bs(qrow[base + j] * scale);
                bqr[n][s][j] = f2bs(qrow[64 + base + j] * scale);
            }
        }
    }

    float mstate[2] = {-INFINITY, -INFINITY};
    float lstate[2] = {0.f, 0.f};
    floatx4 acco[8][2];
    #pragma unroll
    for (int vt = 0; vt < 8; ++vt)
        #pragma unroll
        for (int n = 0; n < 2; ++n)
            acco[vt][n] = (floatx4){0.f, 0.f, 0.f, 0.f};

    int nk = qtile * 2 + 2;
    int qmax_w = q0 + wq + 31;

    for (int kt = 0; kt < nk; ++kt) {
        int k0 = kt * 64;
        #pragma unroll
        for (int it = 0; it < 2; ++it) {
            int c = it * 256 + tid;
            int row = c >> 3, g = c & 7;
            int col = ((g ^ (row & 7)) << 3);
            gload_lds16(KVU + (size_t)(b * S_ + k0 + row) * KVW_ + h * 192 + col, &Kls[c * 8]);
            gload_lds16(KR + (size_t)(b * S_ + k0 + row) * RD_ + col, &Krls[c * 8]);
        }
        #pragma unroll
        for (int it = 0; it < 4; ++it) {
            int c = it * 256 + tid;
            int row = c >> 3, g = c & 7;
            int col = ((g ^ (row & 7)) << 3);
            gload_lds16(VT + ((size_t)bh * 128 + row) * S_ + k0 + col, &Vls[c * 8]);
        }
        __syncthreads();

        if (k0 <= qmax_w) {
            floatx4 sacc[4][2];
            #pragma unroll
            for (int m = 0; m < 4; ++m)
                #pragma unroll
                for (int n = 0; n < 2; ++n)
                    sacc[m][n] = (floatx4){0.f, 0.f, 0.f, 0.f};
            #pragma unroll
            for (int m = 0; m < 4; ++m) {
                short8 ak[2], akr[2];
                #pragma unroll
                for (int s = 0; s < 2; ++s) {
                    ak[s]  = *(const short8*)&Kls[sw(m * 16 + lrow, s * 4 + quad)];
                    akr[s] = *(const short8*)&Krls[sw(m * 16 + lrow, s * 4 + quad)];
                }
                #pragma unroll
                for (int n = 0; n < 2; ++n)
                    #pragma unroll
                    for (int s = 0; s < 2; ++s) {
                        sacc[m][n] = __builtin_amdgcn_mfma_f32_16x16x32_bf16(ak[s],  bq[n][s],  sacc[m][n], 0, 0, 0);
                        sacc[m][n] = __builtin_amdgcn_mfma_f32_16x16x32_bf16(akr[s], bqr[n][s], sacc[m][n], 0, 0, 0);
                    }
            }
            #pragma unroll
            for (int n = 0; n < 2; ++n) {
                int qg = q0 + wq + n * 16 + lrow;
                float tmax = -INFINITY;
                #pragma unroll
                for (int m = 0; m < 4; ++m)
                    #pragma unroll
                    for (int r = 0; r < 4; ++r) {
                        int kg = k0 + m * 16 + quad * 4 + r;
                        if (kg > qg) sacc[m][n][r] = -1e30f;
                        tmax = fmaxf(tmax, sacc[m][n][r]);
                    }
                tmax = fmaxf(tmax, __shfl_xor(tmax, 16));
                tmax = fmaxf(tmax, __shfl_xor(tmax, 32));
                float mnew = fmaxf(mstate[n], tmax);
                float alpha = __expf(mstate[n] - mnew);
                mstate[n] = mnew;
                float ps = 0.f;
                #pragma unroll
                for (int m = 0; m < 4; ++m) {
                    sh4 pk;
                    #pragma unroll
                    for (int r = 0; r < 4; ++r) {
                        float p = __expf(sacc[m][n][r] - mnew);
                        ps += p;
                        pk[r] = f2bs(p);
                    }
                    int qloc = n * 16 + lrow;
                    int off = wid * 2048 + qloc * 64 + (((m * 2 + (quad >> 1)) ^ (lrow & 7)) << 3) + ((quad & 1) << 2);
                    *(sh4*)&Pls[off] = pk;
                }
                ps += __shfl_xor(ps, 16);
                ps += __shfl_xor(ps, 32);
                lstate[n] = lstate[n] * alpha + ps;
                #pragma unroll
                for (int vt = 0; vt < 8; ++vt)
                    #pragma unroll
                    for (int r = 0; r < 4; ++r)
                        acco[vt][n][r] *= alpha;
            }
            short8 bp[2][2];
            #pragma unroll
            for (int n = 0; n < 2; ++n)
                #pragma unroll
                for (int s = 0; s < 2; ++s)
                    bp[n][s] = *(const short8*)&Pls[wid * 2048 + sw(n * 16 + lrow, s * 4 + quad)];
            #pragma unroll
            for (int vt = 0; vt < 8; ++vt) {
                short8 av[2];
                #pragma unroll
                for (int s = 0; s < 2; ++s)
                    av[s] = *(const short8*)&Vls[sw(vt * 16 + lrow, s * 4 + quad)];
                #pragma unroll
                for (int n = 0; n < 2; ++n)
                    #pragma unroll
                    for (int s = 0; s < 2; ++s)
                        acco[vt][n] = __builtin_amdgcn_mfma_f32_16x16x32_bf16(av[s], bp[n][s], acco[vt][n], 0, 0, 0);
            }
        }
        __syncthreads();
    }

    #pragma unroll
    for (int n = 0; n < 2; ++n) {
        float inv = 1.0f / lstate[n];
        int tok = b * S_ + q0 + wq + n * 16 + lrow;
        #pragma unroll
        for (int vt = 0; vt < 8; ++vt) {
            sh4 o4;
            #pragma unroll
            for (int r = 0; r < 4; ++r) o4[r] = f2bs(acco[vt][n][r] * inv);
            *(sh4*)&O[(size_t)tok * D_ + h * DH_ + vt * 16 + quad * 4] = o4;
        }
    }
}

// ---------------- Launcher ----------------
extern "C" void kernel_launch(void* const* d_in, const int* in_sizes, int n_in,
                              void* d_out, int out_size, void* d_ws, size_t ws_size,
                              hipStream_t stream)
{
    const float* x     = (const float*)d_in[0];
    const float* anw   = (const float*)d_in[1];
    const float* anb   = (const float*)d_in[2];
    const float* W_dq  = (const float*)d_in[3];
    const float* qlw   = (const float*)d_in[4];
    const float* qlb   = (const float*)d_in[5];
    const float* W_uq  = (const float*)d_in[6];
    const float* W_dkv = (const float*)d_in[7];
    const float* kvlw  = (const float*)d_in[8];
    const float* kvlb  = (const float*)d_in[9];
    const float* W_ukv = (const float*)d_in[10];
    const float* W_o   = (const float*)d_in[11];
    const float* fnw   = (const float*)d_in[12];
    const float* fnb   = (const float*)d_in[13];
    const float* W1    = (const float*)d_in[14];
    const float* b1    = (const float*)d_in[15];
    const float* W2    = (const float*)d_in[16];
    const float* b2    = (const float*)d_in[17];

    float* out0 = (float*)d_out;                     // [T, D]
    float* ckv  = out0 + (size_t)T_ * D_;            // [T, 1429]

    float* ws = (float*)d_ws;
    float* Q  = ws;                                          // [T,2048] f32
    float* cq = Q + (size_t)T_ * D_;                         // [T,1024] f32
    __hip_bfloat16* kvu_bf = (__hip_bfloat16*)(cq + (size_t)T_ * QP_);  // [T,3072]
    __hip_bfloat16* kr_bf  = kvu_bf + (size_t)T_ * KVW_;     // [T,64]
    __hip_bfloat16* Vt     = kr_bf + (size_t)T_ * RD_;       // [B*H][128][S]
    __hip_bfloat16* h_bf   = Vt + (size_t)T_ * D_;           // [T,2048]
    __hip_bfloat16* cq_bf  = h_bf + (size_t)T_ * D_;         // [T,1024]
    __hip_bfloat16* kvl_bf = cq_bf + (size_t)T_ * QP_;       // [T,1408]
    __hip_bfloat16* o_bf   = kvl_bf + (size_t)T_ * KVP_PAD;  // [T,2048]
    __hip_bfloat16* wdq_t  = o_bf + (size_t)T_ * D_;         // [1024,2048]
    __hip_bfloat16* wuq_t  = wdq_t + (size_t)QP_ * D_;       // [2048,1024]
    __hip_bfloat16* wdkv_t = wuq_t + (size_t)D_ * QP_;       // [1536,2048]
    __hip_bfloat16* wukv_t = wdkv_t + (size_t)CKW_PAD * D_;  // [3072,1408]
    __hip_bfloat16* wo_b   = wukv_t + (size_t)KVW_ * KVP_PAD;// [2048,2048]
    __hip_bfloat16* w1_t   = wo_b + (size_t)D_ * D_;         // [8192,2048]
    __hip_bfloat16* w2_t   = w1_t + (size_t)FF_ * D_;        // [2048,8192]
    __hip_bfloat16* ff1_bf = (__hip_bfloat16*)ws;            // overlays Q+cq+kvu (dead by FFN)

    dim3 blk(256);
    dim3 blk8(512);

    { dim3 g(D_ / 32, QP_ / 32);       transpose_cvt<<<g, blk, 0, stream>>>(W_dq,  wdq_t,  D_, QP_, D_); }
    { dim3 g(QP_ / 32, D_ / 32);       transpose_cvt<<<g, blk, 0, stream>>>(W_uq,  wuq_t,  QP_, D_, QP_); }
    { dim3 g(D_ / 32, CKW_PAD / 32);   transpose_cvt<<<g, blk, 0, stream>>>(W_dkv, wdkv_t, D_, CKW_, D_); }
    { dim3 g(KVP_PAD / 32, KVW_ / 32); transpose_cvt<<<g, blk, 0, stream>>>(W_ukv, wukv_t, KVP_, KVW_, KVP_PAD); }
    { int n = D_ * D_;                 cvt_bf16<<<(n + 255) / 256, blk, 0, stream>>>(W_o, wo_b, n); }
    { dim3 g(D_ / 32, FF_ / 32);       transpose_cvt<<<g, blk, 0, stream>>>(W1, w1_t, D_, FF_, D_); }
    { dim3 g(FF_ / 32, D_ / 32);       transpose_cvt<<<g, blk, 0, stream>>>(W2, w2_t, FF_, D_, FF_); }

    ln_bf16<<<T_, blk, 0, stream>>>(x, D_, anw, anb, h_bf, D_, D_);
    { dim3 g(QP_ / 128, T_ / 128);
      gemm_bf16<0, float><<<g, blk, 0, stream>>>(h_bf, wdq_t, cq, T_, QP_, D_, QP_, nullptr, nullptr); }
    ln_bf16<<<T_, blk, 0, stream>>>(cq, QP_, qlw, qlb, cq_bf, QP_, QP_);
    { dim3 g(D_ / 128, T_ / 128);    // 256^2 grid would be 128 blocks (half chip) -> 128^2
      gemm_bf16<0, float><<<g, blk, 0, stream>>>(cq_bf, wuq_t, Q, T_, D_, QP_, D_, nullptr, nullptr); }
    rope_q_kernel<<<(T_ * H_ * 32) / 256, blk, 0, stream>>>(Q);
    { dim3 g(CKW_PAD / 128, T_ / 128);
      gemm_bf16<0, float><<<g, blk, 0, stream>>>(h_bf, wdkv_t, ckv, T_, CKW_, D_, CKW_, nullptr, nullptr); }
    ln_bf16<<<T_, blk, 0, stream>>>(ckv, CKW_, kvlw, kvlb, kvl_bf, KVP_PAD, KVP_);
    { dim3 g(KVW_ / 256, T_ / 256);  // 192 blocks
      gemm_8ph<0, __hip_bfloat16><<<g, blk8, 0, stream>>>(kvl_bf, wukv_t, kvu_bf, T_, KVW_, KVP_PAD, KVW_, nullptr, nullptr); }
    rope_kr_bf<<<(T_ * 32) / 256, blk, 0, stream>>>(ckv, kr_bf);
    { dim3 g(S_ / 16, B_ * H_);
      vt_pack<<<g, blk, 0, stream>>>(kvu_bf, Vt); }
    { dim3 g(16, B_ * H_);
      attn_mfma<<<g, blk, 0, stream>>>(Q, kvu_bf, kr_bf, Vt, o_bf); }
    { dim3 g(D_ / 128, T_ / 128);    // 128 blocks at 256^2 -> keep 128^2
      gemm_bf16<1, float><<<g, blk, 0, stream>>>(o_bf, wo_b, out0, T_, D_, D_, D_, nullptr, x); }
    ln_bf16<<<T_, blk, 0, stream>>>(out0, D_, fnw, fnb, h_bf, D_, D_);
    { dim3 g(FF_ / 256, T_ / 256);   // 512 blocks, full chip
      gemm_8ph<2, __hip_bfloat16><<<g, blk8, 0, stream>>>(h_bf, w1_t, ff1_bf, T_, FF_, D_, FF_, b1, nullptr); }
    { dim3 g(D_ / 128, T_ / 128);    // 128 blocks at 256^2 -> keep 128^2
      gemm_bf16<3, float><<<g, blk, 0, stream>>>(ff1_bf, w2_t, out0, T_, D_, FF_, D_, b2, nullptr); }
}

// Round 3
// 1054.003 us; speedup vs baseline: 1.4307x; 1.0156x over previous
//
#include <hip/hip_runtime.h>
#include <hip/hip_bf16.h>
#include <math.h>

#define B_ 2
#define S_ 2048
#define D_ 2048
#define H_ 16
#define DH_ 128
#define QP_ 1024
#define KVP_ 1365
#define RD_ 64
#define ND_ 64
#define FF_ 8192
#define T_ (B_*S_)          // 4096 tokens
#define CKW_ (KVP_+RD_)     // 1429
#define KVW_ 3072           // D + H*ND
#define KVP_PAD 1408        // 1365 -> mult of 64
#define CKW_PAD 1536        // 1429 -> mult of 128

typedef __attribute__((ext_vector_type(8))) short short8;
typedef __attribute__((ext_vector_type(4))) short sh4;
typedef __attribute__((ext_vector_type(4))) float floatx4;

__device__ __forceinline__ void gload_lds16(const __hip_bfloat16* g, __hip_bfloat16* l) {
    __builtin_amdgcn_global_load_lds((const __attribute__((address_space(1))) void*)g,
                                     (__attribute__((address_space(3))) void*)l, 16, 0, 0);
}
__device__ __forceinline__ short f2bs(float f) {
    __hip_bfloat16 h = __float2bfloat16(f);
    return *reinterpret_cast<short*>(&h);
}
// XOR-swizzled element offset into a [rows][64] bf16 LDS tile; g = 16B-group (0..7)
__device__ __forceinline__ int sw(int row, int g) { return row * 64 + ((g ^ (row & 7)) << 3); }

// fast gelu: 0.5*v*(1+erf(v/sqrt2)), A&S 7.1.26 erf approx (max err 1.5e-7)
__device__ __forceinline__ float fast_gelu(float v) {
    float x = v * 0.70710678118654752f;
    float ax = fabsf(x);
    float t = __builtin_amdgcn_rcpf(1.f + 0.3275911f * ax);
    float y = t * (0.254829592f + t * (-0.284496736f + t * (1.421413741f + t * (-1.453152027f + t * 1.061405429f))));
    float e = __expf(-ax * ax);
    float erfv = 1.f - y * e;
    erfv = copysignf(erfv, x);
    return 0.5f * v * (1.f + erfv);
}

// ---------------- LayerNorm -> bf16 out with zero-padded stride ----------------
__global__ __launch_bounds__(256) void ln_bf16(const float* __restrict__ in, int in_stride,
                                               const float* __restrict__ w, const float* __restrict__ bb,
                                               __hip_bfloat16* __restrict__ out, int out_stride, int N)
{
    int row = blockIdx.x;
    const float* ip = in + (size_t)row * in_stride;
    __hip_bfloat16* op = out + (size_t)row * out_stride;
    int tid = threadIdx.x;
    __shared__ float s1[256], s2[256];
    float sum = 0.f, sq = 0.f;
    bool vec = (((in_stride | N | out_stride) & 3) == 0);   // block-uniform
    if (vec) {
        const float4* ip4 = (const float4*)ip;
        int n4 = N >> 2;
        for (int i = tid; i < n4; i += 256) {
            float4 v = ip4[i];
            sum += v.x + v.y + v.z + v.w;
            sq  += v.x * v.x + v.y * v.y + v.z * v.z + v.w * v.w;
        }
        s1[tid] = sum; s2[tid] = sq; __syncthreads();
        for (int s = 128; s > 0; s >>= 1) {
            if (tid < s) { s1[tid] += s1[tid + s]; s2[tid] += s2[tid + s]; }
            __syncthreads();
        }
        float mean = s1[0] / N;
        float var  = s2[0] / N - mean * mean;
        float rstd = rsqrtf(var + 1e-5f);
        const float4* w4 = (const float4*)w;
        const float4* b4 = (const float4*)bb;
        for (int i = tid; i < n4; i += 256) {
            float4 v = ip4[i], wv = w4[i], bv = b4[i];
            sh4 o;
            o[0] = f2bs((v.x - mean) * rstd * wv.x + bv.x);
            o[1] = f2bs((v.y - mean) * rstd * wv.y + bv.y);
            o[2] = f2bs((v.z - mean) * rstd * wv.z + bv.z);
            o[3] = f2bs((v.w - mean) * rstd * wv.w + bv.w);
            *(sh4*)&op[i * 4] = o;
        }
    } else {
        for (int i = tid; i < N; i += 256) { float v = ip[i]; sum += v; sq += v * v; }
        s1[tid] = sum; s2[tid] = sq; __syncthreads();
        for (int s = 128; s > 0; s >>= 1) {
            if (tid < s) { s1[tid] += s1[tid + s]; s2[tid] += s2[tid + s]; }
            __syncthreads();
        }
        float mean = s1[0] / N;
        float var  = s2[0] / N - mean * mean;
        float rstd = rsqrtf(var + 1e-5f);
        for (int i = tid; i < N; i += 256) {
            float v = ip[i];
            op[i] = __float2bfloat16((v - mean) * rstd * w[i] + bb[i]);
        }
    }
    for (int i = N + tid; i < out_stride; i += 256) op[i] = __float2bfloat16(0.f);
}

// ---------------- weight transpose + convert: W f32 [K,N] -> Wt bf16 [Npad,Kp] ----------------
__global__ __launch_bounds__(256) void transpose_cvt(const float* __restrict__ W, __hip_bfloat16* __restrict__ Wt,
                                                     int K, int N, int Kp)
{
    __shared__ float t[32][33];
    int k0 = blockIdx.x * 32, n0 = blockIdx.y * 32;
    int tx = threadIdx.x & 31, ty = threadIdx.x >> 5;
    for (int r = ty; r < 32; r += 8) {
        int k = k0 + r, n = n0 + tx;
        t[r][tx] = (k < K && n < N) ? W[(size_t)k * N + n] : 0.f;
    }
    __syncthreads();
    for (int r = ty; r < 32; r += 8) {
        int n = n0 + r, k = k0 + tx;
        Wt[(size_t)n * Kp + k] = __float2bfloat16(t[tx][r]);
    }
}

__global__ __launch_bounds__(256) void cvt_bf16(const float* __restrict__ in, __hip_bfloat16* __restrict__ out, int n)
{
    int i = blockIdx.x * 256 + threadIdx.x;
    if (i < n) out[i] = __float2bfloat16(in[i]);
}

// ---------------- bf16 MFMA GEMM (m97 structure + XOR-swizzled LDS + XCD swizzle) ----------------
template<int EPI, typename CT>
__global__ __launch_bounds__(256) void gemm_bf16(const __hip_bfloat16* __restrict__ A,
                                                 const __hip_bfloat16* __restrict__ Bt,
                                                 CT* __restrict__ C, int M, int N, int Kp, int ldc,
                                                 const float* __restrict__ bias,
                                                 const float* __restrict__ resid)
{
    __shared__ __hip_bfloat16 As[128 * 64];
    __shared__ __hip_bfloat16 Bs[128 * 64];
    int tid = threadIdx.x;
    // XCD chunk swizzle (T1): consecutive slots on one XCD share bm -> A-panel L2 reuse
    int gx = gridDim.x;
    int nwg = gx * gridDim.y;
    int o = blockIdx.y * gx + blockIdx.x;
    int sId = ((nwg & 7) == 0) ? ((o & 7) * (nwg >> 3) + (o >> 3)) : o;
    int bm = (sId / gx) * 128;
    int bn = (sId % gx) * 128;
    int wid = tid >> 6, lane = tid & 63;
    int wm = (wid >> 1) * 64, wn = (wid & 1) * 64;
    int lrow = lane & 15;
    int quad = lane >> 4;

    floatx4 acc[4][4];
    #pragma unroll
    for (int i = 0; i < 4; ++i)
        #pragma unroll
        for (int j = 0; j < 4; ++j)
            acc[i][j] = (floatx4){0.f, 0.f, 0.f, 0.f};

    for (int k0 = 0; k0 < Kp; k0 += 64) {
        #pragma unroll
        for (int it = 0; it < 4; ++it) {
            int chunk = it * 256 + tid;
            int row = chunk >> 3, g = chunk & 7;
            int col = (g ^ (row & 7)) << 3;
            gload_lds16(A + (size_t)(bm + row) * Kp + k0 + col, &As[chunk * 8]);
        }
        #pragma unroll
        for (int it = 0; it < 4; ++it) {
            int chunk = it * 256 + tid;
            int row = chunk >> 3, g = chunk & 7;
            int col = (g ^ (row & 7)) << 3;
            gload_lds16(Bt + (size_t)(bn + row) * Kp + k0 + col, &Bs[chunk * 8]);
        }
        __syncthreads();
        #pragma unroll
        for (int kk = 0; kk < 2; ++kk) {       // k-group s = kk*4 + quad
            short8 a[4], b[4];
            #pragma unroll
            for (int i = 0; i < 4; ++i)
                a[i] = *(const short8*)&As[sw(wm + i * 16 + lrow, kk * 4 + quad)];
            #pragma unroll
            for (int j = 0; j < 4; ++j)
                b[j] = *(const short8*)&Bs[sw(wn + j * 16 + lrow, kk * 4 + quad)];
            #pragma unroll
            for (int i = 0; i < 4; ++i)
                #pragma unroll
                for (int j = 0; j < 4; ++j)
                    acc[i][j] = __builtin_amdgcn_mfma_f32_16x16x32_bf16(a[i], b[j], acc[i][j], 0, 0, 0);
        }
        __syncthreads();
    }

    int cq4 = quad * 4;
    #pragma unroll
    for (int i = 0; i < 4; ++i) {
        #pragma unroll
        for (int j = 0; j < 4; ++j) {
            int col = bn + wn + j * 16 + lrow;
            if (col >= N) continue;
            #pragma unroll
            for (int r = 0; r < 4; ++r) {
                int rowg = bm + wm + i * 16 + cq4 + r;
                float v = acc[i][j][r];
                size_t idx = (size_t)rowg * ldc + col;
                if (EPI == 1) v += resid[idx];
                if (EPI == 2) { v += bias[col]; v = fast_gelu(v); }
                if (EPI == 3) { v += bias[col]; v += ((const float*)C)[idx]; }
                C[idx] = (CT)v;
            }
        }
    }
}

// ---------------- 256x256 8-phase bf16 MFMA GEMM (T1+T2+T3+T4+T5) ----------------
#define BAR8() __builtin_amdgcn_s_barrier()
#define SCB8() __builtin_amdgcn_sched_barrier(0)
#define GATE8(nw) asm volatile("s_waitcnt vmcnt(" #nw ")" ::: "memory")

template<int EPI, typename CT>
__global__ __launch_bounds__(512, 1) void gemm_8ph(const __hip_bfloat16* __restrict__ A,
                                                   const __hip_bfloat16* __restrict__ Bt,
                                                   CT* __restrict__ C, int M, int N, int Kp, int ldc,
                                                   const float* __restrict__ bias,
                                                   const float* __restrict__ resid)
{
    __shared__ __hip_bfloat16 As[2][16384];   // [buf][256 rows * 64]
    __shared__ __hip_bfloat16 Bs[2][16384];

    int tid = threadIdx.x;
    int wid = tid >> 6, lane = tid & 63;
    int lrow = lane & 15, quad = lane >> 4;
    int awm = (wid >> 2) * 128;               // warp_m in {0,1} -> 128-row half
    int bwn = (wid & 3) * 64;                 // warp_n in {0..3} -> 64-col quarter

    // bijective XCD-aware block swizzle (m204)
    int gx = gridDim.x;
    int nwg = gx * gridDim.y;
    int o = blockIdx.y * gx + blockIdx.x;
    int q8 = nwg >> 3, r8 = nwg & 7;
    int xcd = o & 7, oi = o >> 3;
    int s = (xcd < r8 ? xcd * (q8 + 1) : r8 * (q8 + 1) + (xcd - r8) * q8) + oi;
    int bm = (s / gx) * 256, bn = (s % gx) * 256;

    const __hip_bfloat16* Abm = A  + (size_t)bm * Kp;
    const __hip_bfloat16* Bbn = Bt + (size_t)bn * Kp;

    int drow = tid >> 3;                           // row 0..63 within a 64-row round
    int csw  = ((tid & 7) ^ (drow & 7)) << 3;      // pre-swizzled global k-offset
    int ldst = tid * 8;                            // linear LDS dest (elements)

#define STAGE8(srcbase, k0v, dst) do { \
    gload_lds16((srcbase) + (size_t)drow * Kp + (k0v) + csw, (dst) + ldst); \
    gload_lds16((srcbase) + (size_t)(drow + 64) * Kp + (k0v) + csw, (dst) + 4096 + ldst); \
  } while (0)

    int abase = awm + lrow;
    int bbase = bwn + lrow;
    int k0off = ((quad       ^ (lrow & 7)) << 3);
    int k1off = (((4 + quad) ^ (lrow & 7)) << 3);

    short8 af[8][2], bfr[4][2];
    floatx4 acc[8][4];
    #pragma unroll
    for (int m = 0; m < 8; ++m)
        #pragma unroll
        for (int n = 0; n < 4; ++n)
            acc[m][n] = (floatx4){0.f, 0.f, 0.f, 0.f};

#define READ_A8(bufp, mh) do { \
    _Pragma("unroll") \
    for (int m = 0; m < 4; ++m) { \
      const __hip_bfloat16* p_ = (bufp) + (abase + ((mh)*4 + m) * 16) * 64; \
      af[(mh)*4 + m][0] = *(const short8*)(p_ + k0off); \
      af[(mh)*4 + m][1] = *(const short8*)(p_ + k1off); \
    } } while (0)

#define READ_B8(bufp, nh) do { \
    _Pragma("unroll") \
    for (int n = 0; n < 2; ++n) { \
      const __hip_bfloat16* p_ = (bufp) + (bbase + ((nh)*2 + n) * 16) * 64; \
      bfr[(nh)*2 + n][0] = *(const short8*)(p_ + k0off); \
      bfr[(nh)*2 + n][1] = *(const short8*)(p_ + k1off); \
    } } while (0)

#define QMFMA8(mh, nh) do { \
    __builtin_amdgcn_s_setprio(1); \
    _Pragma("unroll") \
    for (int kk = 0; kk < 2; ++kk) \
      _Pragma("unroll") \
      for (int m = 0; m < 4; ++m) \
        _Pragma("unroll") \
        for (int n = 0; n < 2; ++n) \
          acc[(mh)*4 + m][(nh)*2 + n] = __builtin_amdgcn_mfma_f32_16x16x32_bf16( \
              af[(mh)*4 + m][kk], bfr[(nh)*2 + n][kk], acc[(mh)*4 + m][(nh)*2 + n], 0, 0, 0); \
    __builtin_amdgcn_s_setprio(0); \
  } while (0)

    STAGE8(Abm,                   0,  &As[0][0]);
    STAGE8(Abm + (size_t)128*Kp,  0,  &As[0][8192]);
    STAGE8(Bbn,                   0,  &Bs[0][0]);
    STAGE8(Bbn + (size_t)128*Kp,  0,  &Bs[0][8192]);
    STAGE8(Abm,                   64, &As[1][0]);
    STAGE8(Abm + (size_t)128*Kp,  64, &As[1][8192]);
    GATE8(4); SCB8(); BAR8();

    int NT = Kp >> 6;
    #pragma unroll 1
    for (int t = 0; t < NT; t += 2) {
        int kn = (t + 1) << 6;
        int k2 = ((t + 2 < NT) ? t + 2 : NT - 1) << 6;   // tail clamp: staged, never read
        int k3 = ((t + 3 < NT) ? t + 3 : NT - 1) << 6;

        STAGE8(Bbn, kn, &Bs[1][0]);
        READ_A8(&As[0][0], 0); READ_B8(&Bs[0][0], 0);
        SCB8(); BAR8();
        QMFMA8(0, 0);
        SCB8(); BAR8();

        STAGE8(Bbn + (size_t)128*Kp, kn, &Bs[1][8192]);
        READ_B8(&Bs[0][0], 1);
        SCB8(); BAR8();
        QMFMA8(0, 1);
        SCB8(); BAR8();

        READ_A8(&As[0][0], 1);
        SCB8(); BAR8();
        QMFMA8(1, 1);
        SCB8(); BAR8();

        STAGE8(Abm, k2, &As[0][0]);
        STAGE8(Abm + (size_t)128*Kp, k2, &As[0][8192]);
        SCB8(); BAR8();
        QMFMA8(1, 0);
        GATE8(4); SCB8(); BAR8();

        STAGE8(Bbn, k2, &Bs[0][0]);
        READ_A8(&As[1][0], 0); READ_B8(&Bs[1][0], 0);
        SCB8(); BAR8();
        QMFMA8(0, 0);
        SCB8(); BAR8();

        STAGE8(Bbn + (size_t)128*Kp, k2, &Bs[0][8192]);
        READ_B8(&Bs[1][0], 1);
        SCB8(); BAR8();
        QMFMA8(0, 1);
        SCB8(); BAR8();

        READ_A8(&As[1][0], 1);
        SCB8(); BAR8();
        QMFMA8(1, 1);
        SCB8(); BAR8();

        STAGE8(Abm, k3, &As[1][0]);
        STAGE8(Abm + (size_t)128*Kp, k3, &As[1][8192]);
        SCB8(); BAR8();
        QMFMA8(1, 0);
        GATE8(4); SCB8(); BAR8();
    }
    asm volatile("s_waitcnt vmcnt(0)" ::: "memory");

    int cq4 = quad * 4;
    #pragma unroll
    for (int m = 0; m < 8; ++m) {
        int rowg = bm + awm + m * 16 + cq4;
        #pragma unroll
        for (int n = 0; n < 4; ++n) {
            int col = bn + bwn + n * 16 + lrow;
            #pragma unroll
            for (int r = 0; r < 4; ++r) {
                float v = acc[m][n][r];
                size_t idx = (size_t)(rowg + r) * ldc + col;
                if (EPI == 1) v += resid[idx];
                if (EPI == 2) { v += bias[col]; v = fast_gelu(v); }
                if (EPI == 3) { v += bias[col]; v += ((const float*)C)[idx]; }
                C[idx] = (CT)v;
            }
        }
    }
#undef STAGE8
#undef READ_A8
#undef READ_B8
#undef QMFMA8
}

// ---------------- 256x128 8-phase bf16 MFMA GEMM (full-chip grids for N=2048) ----------------
// BM=256, BN=128, BK=64; 8 waves = 2M x 4N -> per-wave 128x32; acc[8][2] (64 VGPR),
// af[8][2] (64), bfr[2][2] (16) -> ~170 regs, fits 256-budget at (512,1). LDS 96 KiB.
// Per tile: A = 4 loads/thread, B = 2. Gate invariant: prologue {A(t0):4,B(t0):2,
// A(t1):4}, GATE(4) leaves A(t1) in flight. ph0/ph4 stage B(+2), ph3/ph7 stage A(+4)
// then GATE(4) drains exactly the next tile's 6 loads. Region safety: As[x] last read
// ph2 (mh1), restaged ph3; Bs[x] last read ph1 (nh1), restaged ph4/ph0 next half.
template<int EPI, typename CT>
__global__ __launch_bounds__(512, 1) void gemm_8ph_n128(const __hip_bfloat16* __restrict__ A,
                                                        const __hip_bfloat16* __restrict__ Bt,
                                                        CT* __restrict__ C, int M, int N, int Kp, int ldc,
                                                        const float* __restrict__ bias,
                                                        const float* __restrict__ resid)
{
    __shared__ __hip_bfloat16 As[2][16384];   // [buf][256 rows * 64]
    __shared__ __hip_bfloat16 Bs[2][8192];    // [buf][128 rows * 64]

    int tid = threadIdx.x;
    int wid = tid >> 6, lane = tid & 63;
    int lrow = lane & 15, quad = lane >> 4;
    int awm = (wid >> 2) * 128;               // warp_m in {0,1} -> 128-row half
    int bwn = (wid & 3) * 32;                 // warp_n in {0..3} -> 32-col slice

    // bijective XCD-aware block swizzle (m204)
    int gx = gridDim.x;
    int nwg = gx * gridDim.y;
    int o = blockIdx.y * gx + blockIdx.x;
    int q8 = nwg >> 3, r8 = nwg & 7;
    int xcd = o & 7, oi = o >> 3;
    int s = (xcd < r8 ? xcd * (q8 + 1) : r8 * (q8 + 1) + (xcd - r8) * q8) + oi;
    int bm = (s / gx) * 256, bn = (s % gx) * 128;

    const __hip_bfloat16* Abm = A  + (size_t)bm * Kp;
    const __hip_bfloat16* Bbn = Bt + (size_t)bn * Kp;

    int drow = tid >> 3;                           // row 0..63 within a 64-row round
    int csw  = ((tid & 7) ^ (drow & 7)) << 3;      // pre-swizzled global k-offset
    int ldst = tid * 8;                            // linear LDS dest (elements)

    // A: 4 rounds of 64 rows (256 rows); B: 2 rounds (128 rows)
#define STAGE_A(k0v, dst) do { \
    gload_lds16(Abm + (size_t)drow * Kp + (k0v) + csw,         (dst) + ldst); \
    gload_lds16(Abm + (size_t)(drow + 64) * Kp + (k0v) + csw,  (dst) + 4096 + ldst); \
    gload_lds16(Abm + (size_t)(drow + 128) * Kp + (k0v) + csw, (dst) + 8192 + ldst); \
    gload_lds16(Abm + (size_t)(drow + 192) * Kp + (k0v) + csw, (dst) + 12288 + ldst); \
  } while (0)
#define STAGE_B(k0v, dst) do { \
    gload_lds16(Bbn + (size_t)drow * Kp + (k0v) + csw,        (dst) + ldst); \
    gload_lds16(Bbn + (size_t)(drow + 64) * Kp + (k0v) + csw, (dst) + 4096 + ldst); \
  } while (0)

    int abase = awm + lrow;
    int bbase = bwn + lrow;
    int k0off = ((quad       ^ (lrow & 7)) << 3);
    int k1off = (((4 + quad) ^ (lrow & 7)) << 3);

    short8 af[8][2], bfr[2][2];
    floatx4 acc[8][2];
    #pragma unroll
    for (int m = 0; m < 8; ++m)
        #pragma unroll
        for (int n = 0; n < 2; ++n)
            acc[m][n] = (floatx4){0.f, 0.f, 0.f, 0.f};

#define READ_A(bufp, mh) do { \
    _Pragma("unroll") \
    for (int m = 0; m < 4; ++m) { \
      const __hip_bfloat16* p_ = (bufp) + (abase + ((mh)*4 + m) * 16) * 64; \
      af[(mh)*4 + m][0] = *(const short8*)(p_ + k0off); \
      af[(mh)*4 + m][1] = *(const short8*)(p_ + k1off); \
    } } while (0)

#define READ_B(bufp, nh) do { \
      const __hip_bfloat16* p_ = (bufp) + (bbase + (nh) * 16) * 64; \
      bfr[nh][0] = *(const short8*)(p_ + k0off); \
      bfr[nh][1] = *(const short8*)(p_ + k1off); \
    } while (0)

#define QMFMA(mh, nh) do { \
    __builtin_amdgcn_s_setprio(1); \
    _Pragma("unroll") \
    for (int kk = 0; kk < 2; ++kk) \
      _Pragma("unroll") \
      for (int m = 0; m < 4; ++m) \
        acc[(mh)*4 + m][nh] = __builtin_amdgcn_mfma_f32_16x16x32_bf16( \
            af[(mh)*4 + m][kk], bfr[nh][kk], acc[(mh)*4 + m][nh], 0, 0, 0); \
    __builtin_amdgcn_s_setprio(0); \
  } while (0)

    // prologue: A(t0):4, B(t0):2, A(t1):4; GATE(4) -> t0 landed, A(t1) in flight
    STAGE_A(0,  &As[0][0]);
    STAGE_B(0,  &Bs[0][0]);
    STAGE_A(64, &As[1][0]);
    GATE8(4); SCB8(); BAR8();

    int NT = Kp >> 6;
    #pragma unroll 1
    for (int t = 0; t < NT; t += 2) {
        int kn = (t + 1) << 6;
        int k2 = ((t + 2 < NT) ? t + 2 : NT - 1) << 6;   // tail clamp: staged, never read
        int k3 = ((t + 3 < NT) ? t + 3 : NT - 1) << 6;

        // ph0: stage B(t+1); read A(t)-mh0 + B(t)-n0; mfma (m0-3, n0)
        STAGE_B(kn, &Bs[1][0]);
        READ_A(&As[0][0], 0); READ_B(&Bs[0][0], 0);
        SCB8(); BAR8();
        QMFMA(0, 0);
        SCB8(); BAR8();
        // ph1: read B-n1; mfma (m0-3, n1)
        READ_B(&Bs[0][0], 1);
        SCB8(); BAR8();
        QMFMA(0, 1);
        SCB8(); BAR8();
        // ph2: read A-mh1; mfma (m4-7, n1)
        READ_A(&As[0][0], 1);
        SCB8(); BAR8();
        QMFMA(1, 1);
        SCB8(); BAR8();
        // ph3: stage A(t+2) (As[0] fully read by ph2); mfma (m4-7, n0);
        //      GATE(4): A(t+1)+B(t+1) landed, A(t+2) in flight
        STAGE_A(k2, &As[0][0]);
        SCB8(); BAR8();
        QMFMA(1, 0);
        GATE8(4); SCB8(); BAR8();
        // ph4-7: tile t+1 from As[1]/Bs[1]
        STAGE_B(k2, &Bs[0][0]);
        READ_A(&As[1][0], 0); READ_B(&Bs[1][0], 0);
        SCB8(); BAR8();
        QMFMA(0, 0);
        SCB8(); BAR8();

        READ_B(&Bs[1][0], 1);
        SCB8(); BAR8();
        QMFMA(0, 1);
        SCB8(); BAR8();

        READ_A(&As[1][0], 1);
        SCB8(); BAR8();
        QMFMA(1, 1);
        SCB8(); BAR8();

        STAGE_A(k3, &As[1][0]);
        SCB8(); BAR8();
        QMFMA(1, 0);
        GATE8(4); SCB8(); BAR8();
    }
    asm volatile("s_waitcnt vmcnt(0)" ::: "memory");

    int cq4 = quad * 4;
    #pragma unroll
    for (int m = 0; m < 8; ++m) {
        int rowg = bm + awm + m * 16 + cq4;
        #pragma unroll
        for (int n = 0; n < 2; ++n) {
            int col = bn + bwn + n * 16 + lrow;
            #pragma unroll
            for (int r = 0; r < 4; ++r) {
                float v = acc[m][n][r];
                size_t idx = (size_t)(rowg + r) * ldc + col;
                if (EPI == 1) v += resid[idx];
                if (EPI == 2) { v += bias[col]; v = fast_gelu(v); }
                if (EPI == 3) { v += bias[col]; v += ((const float*)C)[idx]; }
                C[idx] = (CT)v;
            }
        }
    }
#undef STAGE_A
#undef STAGE_B
#undef READ_A
#undef READ_B
#undef QMFMA
}

// ---------------- RoPE ----------------
__global__ __launch_bounds__(256) void rope_q_kernel(float* __restrict__ Q)
{
    int idx = blockIdx.x * 256 + threadIdx.x;        // T*H*32
    int i = idx & 31;
    int h = (idx >> 5) & (H_ - 1);
    int t = idx >> 9;
    float f = expf(-(float)i * (9.210340371976184f / 64.0f));
    float ang = (float)(t & (S_ - 1)) * f;
    float sv, cv; sincosf(ang, &sv, &cv);
    float* p = Q + (size_t)t * D_ + h * DH_ + ND_;
    float u = p[i], v = p[i + 32];
    p[i]      = u * cv - v * sv;
    p[i + 32] = v * cv + u * sv;
}

__global__ __launch_bounds__(256) void rope_kr_bf(const float* __restrict__ ckv, __hip_bfloat16* __restrict__ kr)
{
    int idx = blockIdx.x * 256 + threadIdx.x;        // T*32
    int i = idx & 31;
    int t = idx >> 5;
    float f = expf(-(float)i * (9.210340371976184f / 64.0f));
    float ang = (float)(t & (S_ - 1)) * f;
    float sv, cv; sincosf(ang, &sv, &cv);
    const float* src = ckv + (size_t)t * CKW_ + KVP_;
    float u = src[i], v = src[i + 32];
    kr[(size_t)t * RD_ + i]      = __float2bfloat16(u * cv - v * sv);
    kr[(size_t)t * RD_ + i + 32] = __float2bfloat16(v * cv + u * sv);
}

// ---------------- V transpose: kvu[t][h*192+64+v] -> Vt[b*H+h][v][t] (bf16) ----------------
__global__ __launch_bounds__(256) void vt_pack(const __hip_bfloat16* __restrict__ kvu,
                                               __hip_bfloat16* __restrict__ Vt)
{
    int bh = blockIdx.y; int b = bh >> 4, h = bh & 15;
    int v = threadIdx.x & 127;
    int tg = blockIdx.x * 2 + (threadIdx.x >> 7);
    int t0 = tg * 8;
    short8 o;
    #pragma unroll
    for (int j = 0; j < 8; ++j) {
        __hip_bfloat16 e = kvu[(size_t)(b * S_ + t0 + j) * KVW_ + h * 192 + 64 + v];
        o[j] = *reinterpret_cast<short*>(&e);
    }
    *(short8*)&Vt[((size_t)bh * 128 + v) * S_ + t0] = o;
}

// ---------------- Flash MFMA attention (+ XCD chunk swizzle: same bh -> same XCD) ----
__global__ __launch_bounds__(256) void attn_mfma(const float* __restrict__ Q,
                                                 const __hip_bfloat16* __restrict__ KVU,
                                                 const __hip_bfloat16* __restrict__ KR,
                                                 const __hip_bfloat16* __restrict__ VT,
                                                 __hip_bfloat16* __restrict__ O)
{
    __shared__ __hip_bfloat16 Kls[64 * 64];
    __shared__ __hip_bfloat16 Krls[64 * 64];
    __shared__ __hip_bfloat16 Vls[128 * 64];
    __shared__ __hip_bfloat16 Pls[4 * 32 * 64];

    int tid = threadIdx.x, wid = tid >> 6, lane = tid & 63;
    int lrow = lane & 15, quad = lane >> 4;
    int kq8 = quad * 8;
    // chunk swizzle: nwg = 512 (16 x 32); XCD k gets 4 consecutive bh values
    int o = blockIdx.y * 16 + blockIdx.x;
    int sId = (o & 7) * 64 + (o >> 3);
    int qtile = 15 - (sId & 15);
    int bh = sId >> 4;
    int b = bh >> 4, h = bh & 15;
    int q0 = qtile * 128, wq = wid * 32;

    const float scale = 0.08838834764831845f;

    short8 bq[2][2], bqr[2][2];
    #pragma unroll
    for (int n = 0; n < 2; ++n) {
        const float* qrow = Q + (size_t)(b * S_ + q0 + wq + n * 16 + lrow) * D_ + h * DH_;
        #pragma unroll
        for (int s = 0; s < 2; ++s) {
            int base = s * 32 + kq8;
            #pragma unroll
            for (int j = 0; j < 8; ++j) {
                bq[n][s][j]  = f2bs(qrow[base + j] * scale);
                bqr[n][s][j] = f2bs(qrow[64 + base + j] * scale);
            }
        }
    }

    float mstate[2] = {-INFINITY, -INFINITY};
    float lstate[2] = {0.f, 0.f};
    floatx4 acco[8][2];
    #pragma unroll
    for (int vt = 0; vt < 8; ++vt)
        #pragma unroll
        for (int n = 0; n < 2; ++n)
            acco[vt][n] = (floatx4){0.f, 0.f, 0.f, 0.f};

    int nk = qtile * 2 + 2;
    int qmax_w = q0 + wq + 31;

    for (int kt = 0; kt < nk; ++kt) {
        int k0 = kt * 64;
        #pragma unroll
        for (int it = 0; it < 2; ++it) {
            int c = it * 256 + tid;
            int row = c >> 3, g = c & 7;
            int col = ((g ^ (row & 7)) << 3);
            gload_lds16(KVU + (size_t)(b * S_ + k0 + row) * KVW_ + h * 192 + col, &Kls[c * 8]);
            gload_lds16(KR + (size_t)(b * S_ + k0 + row) * RD_ + col, &Krls[c * 8]);
        }
        #pragma unroll
        for (int it = 0; it < 4; ++it) {
            int c = it * 256 + tid;
            int row = c >> 3, g = c & 7;
            int col = ((g ^ (row & 7)) << 3);
            gload_lds16(VT + ((size_t)bh * 128 + row) * S_ + k0 + col, &Vls[c * 8]);
        }
        __syncthreads();

        if (k0 <= qmax_w) {
            floatx4 sacc[4][2];
            #pragma unroll
            for (int m = 0; m < 4; ++m)
                #pragma unroll
                for (int n = 0; n < 2; ++n)
                    sacc[m][n] = (floatx4){0.f, 0.f, 0.f, 0.f};
            #pragma unroll
            for (int m = 0; m < 4; ++m) {
                short8 ak[2], akr[2];
                #pragma unroll
                for (int s = 0; s < 2; ++s) {
                    ak[s]  = *(const short8*)&Kls[sw(m * 16 + lrow, s * 4 + quad)];
                    akr[s] = *(const short8*)&Krls[sw(m * 16 + lrow, s * 4 + quad)];
                }
                #pragma unroll
                for (int n = 0; n < 2; ++n)
                    #pragma unroll
                    for (int s = 0; s < 2; ++s) {
                        sacc[m][n] = __builtin_amdgcn_mfma_f32_16x16x32_bf16(ak[s],  bq[n][s],  sacc[m][n], 0, 0, 0);
                        sacc[m][n] = __builtin_amdgcn_mfma_f32_16x16x32_bf16(akr[s], bqr[n][s], sacc[m][n], 0, 0, 0);
                    }
            }
            #pragma unroll
            for (int n = 0; n < 2; ++n) {
                int qg = q0 + wq + n * 16 + lrow;
                float tmax = -INFINITY;
                #pragma unroll
                for (int m = 0; m < 4; ++m)
                    #pragma unroll
                    for (int r = 0; r < 4; ++r) {
                        int kg = k0 + m * 16 + quad * 4 + r;
                        if (kg > qg) sacc[m][n][r] = -1e30f;
                        tmax = fmaxf(tmax, sacc[m][n][r]);
                    }
                tmax = fmaxf(tmax, __shfl_xor(tmax, 16));
                tmax = fmaxf(tmax, __shfl_xor(tmax, 32));
                float mnew = fmaxf(mstate[n], tmax);
                float alpha = __expf(mstate[n] - mnew);
                mstate[n] = mnew;
                float ps = 0.f;
                #pragma unroll
                for (int m = 0; m < 4; ++m) {
                    sh4 pk;
                    #pragma unroll
                    for (int r = 0; r < 4; ++r) {
                        float p = __expf(sacc[m][n][r] - mnew);
                        ps += p;
                        pk[r] = f2bs(p);
                    }
                    int qloc = n * 16 + lrow;
                    int off = wid * 2048 + qloc * 64 + (((m * 2 + (quad >> 1)) ^ (lrow & 7)) << 3) + ((quad & 1) << 2);
                    *(sh4*)&Pls[off] = pk;
                }
                ps += __shfl_xor(ps, 16);
                ps += __shfl_xor(ps, 32);
                lstate[n] = lstate[n] * alpha + ps;
                #pragma unroll
                for (int vt = 0; vt < 8; ++vt)
                    #pragma unroll
                    for (int r = 0; r < 4; ++r)
                        acco[vt][n][r] *= alpha;
            }
            short8 bp[2][2];
            #pragma unroll
            for (int n = 0; n < 2; ++n)
                #pragma unroll
                for (int s = 0; s < 2; ++s)
                    bp[n][s] = *(const short8*)&Pls[wid * 2048 + sw(n * 16 + lrow, s * 4 + quad)];
            #pragma unroll
            for (int vt = 0; vt < 8; ++vt) {
                short8 av[2];
                #pragma unroll
                for (int s = 0; s < 2; ++s)
                    av[s] = *(const short8*)&Vls[sw(vt * 16 + lrow, s * 4 + quad)];
                #pragma unroll
                for (int n = 0; n < 2; ++n)
                    #pragma unroll
                    for (int s = 0; s < 2; ++s)
                        acco[vt][n] = __builtin_amdgcn_mfma_f32_16x16x32_bf16(av[s], bp[n][s], acco[vt][n], 0, 0, 0);
            }
        }
        __syncthreads();
    }

    #pragma unroll
    for (int n = 0; n < 2; ++n) {
        float inv = 1.0f / lstate[n];
        int tok = b * S_ + q0 + wq + n * 16 + lrow;
        #pragma unroll
        for (int vt = 0; vt < 8; ++vt) {
            sh4 o4;
            #pragma unroll
            for (int r = 0; r < 4; ++r) o4[r] = f2bs(acco[vt][n][r] * inv);
            *(sh4*)&O[(size_t)tok * D_ + h * DH_ + vt * 16 + quad * 4] = o4;
        }
    }
}

// ---------------- Launcher ----------------
extern "C" void kernel_launch(void* const* d_in, const int* in_sizes, int n_in,
                              void* d_out, int out_size, void* d_ws, size_t ws_size,
                              hipStream_t stream)
{
    const float* x     = (const float*)d_in[0];
    const float* anw   = (const float*)d_in[1];
    const float* anb   = (const float*)d_in[2];
    const float* W_dq  = (const float*)d_in[3];
    const float* qlw   = (const float*)d_in[4];
    const float* qlb   = (const float*)d_in[5];
    const float* W_uq  = (const float*)d_in[6];
    const float* W_dkv = (const float*)d_in[7];
    const float* kvlw  = (const float*)d_in[8];
    const float* kvlb  = (const float*)d_in[9];
    const float* W_ukv = (const float*)d_in[10];
    const float* W_o   = (const float*)d_in[11];
    const float* fnw   = (const float*)d_in[12];
    const float* fnb   = (const float*)d_in[13];
    const float* W1    = (const float*)d_in[14];
    const float* b1    = (const float*)d_in[15];
    const float* W2    = (const float*)d_in[16];
    const float* b2    = (const float*)d_in[17];

    float* out0 = (float*)d_out;                     // [T, D]
    float* ckv  = out0 + (size_t)T_ * D_;            // [T, 1429]

    float* ws = (float*)d_ws;
    float* Q  = ws;                                          // [T,2048] f32
    float* cq = Q + (size_t)T_ * D_;                         // [T,1024] f32
    __hip_bfloat16* kvu_bf = (__hip_bfloat16*)(cq + (size_t)T_ * QP_);  // [T,3072]
    __hip_bfloat16* kr_bf  = kvu_bf + (size_t)T_ * KVW_;     // [T,64]
    __hip_bfloat16* Vt     = kr_bf + (size_t)T_ * RD_;       // [B*H][128][S]
    __hip_bfloat16* h_bf   = Vt + (size_t)T_ * D_;           // [T,2048]
    __hip_bfloat16* cq_bf  = h_bf + (size_t)T_ * D_;         // [T,1024]
    __hip_bfloat16* kvl_bf = cq_bf + (size_t)T_ * QP_;       // [T,1408]
    __hip_bfloat16* o_bf   = kvl_bf + (size_t)T_ * KVP_PAD;  // [T,2048]
    __hip_bfloat16* wdq_t  = o_bf + (size_t)T_ * D_;         // [1024,2048]
    __hip_bfloat16* wuq_t  = wdq_t + (size_t)QP_ * D_;       // [2048,1024]
    __hip_bfloat16* wdkv_t = wuq_t + (size_t)D_ * QP_;       // [1536,2048]
    __hip_bfloat16* wukv_t = wdkv_t + (size_t)CKW_PAD * D_;  // [3072,1408]
    __hip_bfloat16* wo_b   = wukv_t + (size_t)KVW_ * KVP_PAD;// [2048,2048]
    __hip_bfloat16* w1_t   = wo_b + (size_t)D_ * D_;         // [8192,2048]
    __hip_bfloat16* w2_t   = w1_t + (size_t)FF_ * D_;        // [2048,8192]
    __hip_bfloat16* ff1_bf = (__hip_bfloat16*)ws;            // overlays Q+cq+kvu (dead by FFN)

    dim3 blk(256);
    dim3 blk8(512);

    { dim3 g(D_ / 32, QP_ / 32);       transpose_cvt<<<g, blk, 0, stream>>>(W_dq,  wdq_t,  D_, QP_, D_); }
    { dim3 g(QP_ / 32, D_ / 32);       transpose_cvt<<<g, blk, 0, stream>>>(W_uq,  wuq_t,  QP_, D_, QP_); }
    { dim3 g(D_ / 32, CKW_PAD / 32);   transpose_cvt<<<g, blk, 0, stream>>>(W_dkv, wdkv_t, D_, CKW_, D_); }
    { dim3 g(KVP_PAD / 32, KVW_ / 32); transpose_cvt<<<g, blk, 0, stream>>>(W_ukv, wukv_t, KVP_, KVW_, KVP_PAD); }
    { int n = D_ * D_;                 cvt_bf16<<<(n + 255) / 256, blk, 0, stream>>>(W_o, wo_b, n); }
    { dim3 g(D_ / 32, FF_ / 32);       transpose_cvt<<<g, blk, 0, stream>>>(W1, w1_t, D_, FF_, D_); }
    { dim3 g(FF_ / 32, D_ / 32);       transpose_cvt<<<g, blk, 0, stream>>>(W2, w2_t, FF_, D_, FF_); }

    ln_bf16<<<T_, blk, 0, stream>>>(x, D_, anw, anb, h_bf, D_, D_);
    { dim3 g(QP_ / 128, T_ / 128);
      gemm_bf16<0, float><<<g, blk, 0, stream>>>(h_bf, wdq_t, cq, T_, QP_, D_, QP_, nullptr, nullptr); }
    ln_bf16<<<T_, blk, 0, stream>>>(cq, QP_, qlw, qlb, cq_bf, QP_, QP_);
    { dim3 g(D_ / 128, T_ / 256);    // 16 x 16 = 256 blocks, full chip
      gemm_8ph_n128<0, float><<<g, blk8, 0, stream>>>(cq_bf, wuq_t, Q, T_, D_, QP_, D_, nullptr, nullptr); }
    rope_q_kernel<<<(T_ * H_ * 32) / 256, blk, 0, stream>>>(Q);
    { dim3 g(CKW_PAD / 128, T_ / 128);
      gemm_bf16<0, float><<<g, blk, 0, stream>>>(h_bf, wdkv_t, ckv, T_, CKW_, D_, CKW_, nullptr, nullptr); }
    ln_bf16<<<T_, blk, 0, stream>>>(ckv, CKW_, kvlw, kvlb, kvl_bf, KVP_PAD, KVP_);
    { dim3 g(KVW_ / 256, T_ / 256);  // 192 blocks
      gemm_8ph<0, __hip_bfloat16><<<g, blk8, 0, stream>>>(kvl_bf, wukv_t, kvu_bf, T_, KVW_, KVP_PAD, KVW_, nullptr, nullptr); }
    rope_kr_bf<<<(T_ * 32) / 256, blk, 0, stream>>>(ckv, kr_bf);
    { dim3 g(S_ / 16, B_ * H_);
      vt_pack<<<g, blk, 0, stream>>>(kvu_bf, Vt); }
    { dim3 g(16, B_ * H_);
      attn_mfma<<<g, blk, 0, stream>>>(Q, kvu_bf, kr_bf, Vt, o_bf); }
    { dim3 g(D_ / 128, T_ / 256);    // 256 blocks, full chip
      gemm_8ph_n128<1, float><<<g, blk8, 0, stream>>>(o_bf, wo_b, out0, T_, D_, D_, D_, nullptr, x); }
    ln_bf16<<<T_, blk, 0, stream>>>(out0, D_, fnw, fnb, h_bf, D_, D_);
    { dim3 g(FF_ / 256, T_ / 256);   // 512 blocks, full chip
      gemm_8ph<2, __hip_bfloat16><<<g, blk8, 0, stream>>>(h_bf, w1_t, ff1_bf, T_, FF_, D_, FF_, b1, nullptr); }
    { dim3 g(D_ / 128, T_ / 256);    // 256 blocks, full chip
      gemm_8ph_n128<3, float><<<g, blk8, 0, stream>>>(ff1_bf, w2_t, out0, T_, D_, FF_, D_, b2, nullptr); }
}

// Round 4
// 999.082 us; speedup vs baseline: 1.5094x; 1.0550x over previous
//
#include <hip/hip_runtime.h>
#include <hip/hip_bf16.h>
#include <math.h>

#define B_ 2
#define S_ 2048
#define D_ 2048
#define H_ 16
#define DH_ 128
#define QP_ 1024
#define KVP_ 1365
#define RD_ 64
#define ND_ 64
#define FF_ 8192
#define T_ (B_*S_)          // 4096 tokens
#define CKW_ (KVP_+RD_)     // 1429
#define KVW_ 3072           // D + H*ND
#define KVP_PAD 1408        // 1365 -> mult of 64
#define CKW_PAD 1536        // 1429 -> mult of 128

typedef __attribute__((ext_vector_type(8))) short short8;
typedef __attribute__((ext_vector_type(4))) short sh4;
typedef __attribute__((ext_vector_type(4))) float floatx4;

__device__ __forceinline__ void gload_lds16(const __hip_bfloat16* g, __hip_bfloat16* l) {
    __builtin_amdgcn_global_load_lds((const __attribute__((address_space(1))) void*)g,
                                     (__attribute__((address_space(3))) void*)l, 16, 0, 0);
}
__device__ __forceinline__ short f2bs(float f) {
    __hip_bfloat16 h = __float2bfloat16(f);
    return *reinterpret_cast<short*>(&h);
}
// XOR-swizzled element offset into a [rows][64] bf16 LDS tile; g = 16B-group (0..7)
__device__ __forceinline__ int sw(int row, int g) { return row * 64 + ((g ^ (row & 7)) << 3); }

// fast gelu: 0.5*v*(1+erf(v/sqrt2)), A&S 7.1.26 erf approx (max err 1.5e-7)
__device__ __forceinline__ float fast_gelu(float v) {
    float x = v * 0.70710678118654752f;
    float ax = fabsf(x);
    float t = __builtin_amdgcn_rcpf(1.f + 0.3275911f * ax);
    float y = t * (0.254829592f + t * (-0.284496736f + t * (1.421413741f + t * (-1.453152027f + t * 1.061405429f))));
    float e = __expf(-ax * ax);
    float erfv = 1.f - y * e;
    erfv = copysignf(erfv, x);
    return 0.5f * v * (1.f + erfv);
}

// ---------------- LayerNorm -> bf16 out with zero-padded stride ----------------
__global__ __launch_bounds__(256) void ln_bf16(const float* __restrict__ in, int in_stride,
                                               const float* __restrict__ w, const float* __restrict__ bb,
                                               __hip_bfloat16* __restrict__ out, int out_stride, int N)
{
    int row = blockIdx.x;
    const float* ip = in + (size_t)row * in_stride;
    __hip_bfloat16* op = out + (size_t)row * out_stride;
    int tid = threadIdx.x;
    __shared__ float s1[256], s2[256];
    float sum = 0.f, sq = 0.f;
    bool vec = (((in_stride | N | out_stride) & 3) == 0);   // block-uniform
    if (vec) {
        const float4* ip4 = (const float4*)ip;
        int n4 = N >> 2;
        for (int i = tid; i < n4; i += 256) {
            float4 v = ip4[i];
            sum += v.x + v.y + v.z + v.w;
            sq  += v.x * v.x + v.y * v.y + v.z * v.z + v.w * v.w;
        }
        s1[tid] = sum; s2[tid] = sq; __syncthreads();
        for (int s = 128; s > 0; s >>= 1) {
            if (tid < s) { s1[tid] += s1[tid + s]; s2[tid] += s2[tid + s]; }
            __syncthreads();
        }
        float mean = s1[0] / N;
        float var  = s2[0] / N - mean * mean;
        float rstd = rsqrtf(var + 1e-5f);
        const float4* w4 = (const float4*)w;
        const float4* b4 = (const float4*)bb;
        for (int i = tid; i < n4; i += 256) {
            float4 v = ip4[i], wv = w4[i], bv = b4[i];
            sh4 o;
            o[0] = f2bs((v.x - mean) * rstd * wv.x + bv.x);
            o[1] = f2bs((v.y - mean) * rstd * wv.y + bv.y);
            o[2] = f2bs((v.z - mean) * rstd * wv.z + bv.z);
            o[3] = f2bs((v.w - mean) * rstd * wv.w + bv.w);
            *(sh4*)&op[i * 4] = o;
        }
    } else {
        for (int i = tid; i < N; i += 256) { float v = ip[i]; sum += v; sq += v * v; }
        s1[tid] = sum; s2[tid] = sq; __syncthreads();
        for (int s = 128; s > 0; s >>= 1) {
            if (tid < s) { s1[tid] += s1[tid + s]; s2[tid] += s2[tid + s]; }
            __syncthreads();
        }
        float mean = s1[0] / N;
        float var  = s2[0] / N - mean * mean;
        float rstd = rsqrtf(var + 1e-5f);
        for (int i = tid; i < N; i += 256) {
            float v = ip[i];
            op[i] = __float2bfloat16((v - mean) * rstd * w[i] + bb[i]);
        }
    }
    for (int i = N + tid; i < out_stride; i += 256) op[i] = __float2bfloat16(0.f);
}

// ---------------- weight transpose + convert: W f32 [K,N] -> Wt bf16 [Npad,Kp] ----------------
__global__ __launch_bounds__(256) void transpose_cvt(const float* __restrict__ W, __hip_bfloat16* __restrict__ Wt,
                                                     int K, int N, int Kp)
{
    __shared__ float t[32][33];
    int k0 = blockIdx.x * 32, n0 = blockIdx.y * 32;
    int tx = threadIdx.x & 31, ty = threadIdx.x >> 5;
    for (int r = ty; r < 32; r += 8) {
        int k = k0 + r, n = n0 + tx;
        t[r][tx] = (k < K && n < N) ? W[(size_t)k * N + n] : 0.f;
    }
    __syncthreads();
    for (int r = ty; r < 32; r += 8) {
        int n = n0 + r, k = k0 + tx;
        Wt[(size_t)n * Kp + k] = __float2bfloat16(t[tx][r]);
    }
}

__global__ __launch_bounds__(256) void cvt_bf16(const float* __restrict__ in, __hip_bfloat16* __restrict__ out, int n)
{
    int i = blockIdx.x * 256 + threadIdx.x;
    if (i < n) out[i] = __float2bfloat16(in[i]);
}

// ---------------- bf16 MFMA GEMM (m97 structure + XOR-swizzled LDS + XCD swizzle) ----------------
template<int EPI, typename CT>
__global__ __launch_bounds__(256) void gemm_bf16(const __hip_bfloat16* __restrict__ A,
                                                 const __hip_bfloat16* __restrict__ Bt,
                                                 CT* __restrict__ C, int M, int N, int Kp, int ldc,
                                                 const float* __restrict__ bias,
                                                 const float* __restrict__ resid)
{
    __shared__ __hip_bfloat16 As[128 * 64];
    __shared__ __hip_bfloat16 Bs[128 * 64];
    int tid = threadIdx.x;
    int gx = gridDim.x;
    int nwg = gx * gridDim.y;
    int o = blockIdx.y * gx + blockIdx.x;
    int sId = ((nwg & 7) == 0) ? ((o & 7) * (nwg >> 3) + (o >> 3)) : o;
    int bm = (sId / gx) * 128;
    int bn = (sId % gx) * 128;
    int wid = tid >> 6, lane = tid & 63;
    int wm = (wid >> 1) * 64, wn = (wid & 1) * 64;
    int lrow = lane & 15;
    int quad = lane >> 4;

    floatx4 acc[4][4];
    #pragma unroll
    for (int i = 0; i < 4; ++i)
        #pragma unroll
        for (int j = 0; j < 4; ++j)
            acc[i][j] = (floatx4){0.f, 0.f, 0.f, 0.f};

    for (int k0 = 0; k0 < Kp; k0 += 64) {
        #pragma unroll
        for (int it = 0; it < 4; ++it) {
            int chunk = it * 256 + tid;
            int row = chunk >> 3, g = chunk & 7;
            int col = (g ^ (row & 7)) << 3;
            gload_lds16(A + (size_t)(bm + row) * Kp + k0 + col, &As[chunk * 8]);
        }
        #pragma unroll
        for (int it = 0; it < 4; ++it) {
            int chunk = it * 256 + tid;
            int row = chunk >> 3, g = chunk & 7;
            int col = (g ^ (row & 7)) << 3;
            gload_lds16(Bt + (size_t)(bn + row) * Kp + k0 + col, &Bs[chunk * 8]);
        }
        __syncthreads();
        #pragma unroll
        for (int kk = 0; kk < 2; ++kk) {       // k-group s = kk*4 + quad
            short8 a[4], b[4];
            #pragma unroll
            for (int i = 0; i < 4; ++i)
                a[i] = *(const short8*)&As[sw(wm + i * 16 + lrow, kk * 4 + quad)];
            #pragma unroll
            for (int j = 0; j < 4; ++j)
                b[j] = *(const short8*)&Bs[sw(wn + j * 16 + lrow, kk * 4 + quad)];
            #pragma unroll
            for (int i = 0; i < 4; ++i)
                #pragma unroll
                for (int j = 0; j < 4; ++j)
                    acc[i][j] = __builtin_amdgcn_mfma_f32_16x16x32_bf16(a[i], b[j], acc[i][j], 0, 0, 0);
        }
        __syncthreads();
    }

    int cq4 = quad * 4;
    #pragma unroll
    for (int i = 0; i < 4; ++i) {
        #pragma unroll
        for (int j = 0; j < 4; ++j) {
            int col = bn + wn + j * 16 + lrow;
            if (col >= N) continue;
            #pragma unroll
            for (int r = 0; r < 4; ++r) {
                int rowg = bm + wm + i * 16 + cq4 + r;
                float v = acc[i][j][r];
                size_t idx = (size_t)rowg * ldc + col;
                if (EPI == 1) v += resid[idx];
                if (EPI == 2) { v += bias[col]; v = fast_gelu(v); }
                if (EPI == 3) { v += bias[col]; v += ((const float*)C)[idx]; }
                C[idx] = (CT)v;
            }
        }
    }
}

// ---------------- 256x128 cross-phase-pipelined bf16 MFMA GEMM ----------------
// Round-3 post-mortem model: barrier-lockstep phases SERIALIZE LDS-read time and
// MFMA time (3515 cyc/K-tile = 1600 LDS + 1242 MFMA + barriers). Fixes here:
//  (a) per-wave 64x64 (4M x 2N): 16 ds_read per 32 MFMA (was 20/32 at 128x32)
//  (b) cross-phase register pipelining: phase p issues ds_reads for phase p+1's
//      kk-cluster, then MFMAs on regs read last phase -> LDS pipe under MFMA pipe
//  (c) triple-buffered LDS (A 3x32K + B 3x16K = 144 KiB): stage t+2 never touches
//      the two buffers being read (t, t+1); only 2 barriers per K-tile.
// Gate invariant: stages/tile = 6 (A:4, B:2); at GATE(6) in-flight = t+1(6)+t+2(6)
// -> waits exactly t+1; BAR after gate makes all waves' loads visible before the
// read-ahead of tile t+1. Buffer (t+2)%3's last reads (tile t-1's kk1) lgkm-complete
// before tile t-1's end barrier -> restage in tile t is >=1 barrier later.
#define BARP() __builtin_amdgcn_s_barrier()
#define SCBP() __builtin_amdgcn_sched_barrier(0)
#define GATEP(nw) asm volatile("s_waitcnt vmcnt(" #nw ")" ::: "memory")

template<int EPI, typename CT>
__global__ __launch_bounds__(512, 1) void gemm_pp(const __hip_bfloat16* __restrict__ A,
                                                  const __hip_bfloat16* __restrict__ Bt,
                                                  CT* __restrict__ C, int M, int N, int Kp, int ldc,
                                                  const float* __restrict__ bias,
                                                  const float* __restrict__ resid)
{
    __shared__ __hip_bfloat16 As[3][16384];   // [buf][256 rows * 64]
    __shared__ __hip_bfloat16 Bs[3][8192];    // [buf][128 rows * 64]

    int tid = threadIdx.x;
    int wid = tid >> 6, lane = tid & 63;
    int lrow = lane & 15, quad = lane >> 4;
    int awm = (wid >> 1) * 64;                // 4 M-positions
    int bwn = (wid & 1) * 64;                 // 2 N-positions

    // bijective XCD-aware block swizzle (m204)
    int gx = gridDim.x;
    int nwg = gx * gridDim.y;
    int o = blockIdx.y * gx + blockIdx.x;
    int q8 = nwg >> 3, r8 = nwg & 7;
    int xcd = o & 7, oi = o >> 3;
    int s = (xcd < r8 ? xcd * (q8 + 1) : r8 * (q8 + 1) + (xcd - r8) * q8) + oi;
    int bm = (s / gx) * 256, bn = (s % gx) * 128;

    const __hip_bfloat16* Abm = A  + (size_t)bm * Kp;
    const __hip_bfloat16* Bbn = Bt + (size_t)bn * Kp;

    int drow = tid >> 3;                           // row 0..63 within a 64-row round
    int csw  = ((tid & 7) ^ (drow & 7)) << 3;      // pre-swizzled global k-offset
    int ldst = tid * 8;                            // linear LDS dest (elements)

#define PSTAGE_A(k0v, dst) do { \
    gload_lds16(Abm + (size_t)drow * Kp + (k0v) + csw,         (dst) + ldst); \
    gload_lds16(Abm + (size_t)(drow + 64) * Kp + (k0v) + csw,  (dst) + 4096 + ldst); \
    gload_lds16(Abm + (size_t)(drow + 128) * Kp + (k0v) + csw, (dst) + 8192 + ldst); \
    gload_lds16(Abm + (size_t)(drow + 192) * Kp + (k0v) + csw, (dst) + 12288 + ldst); \
  } while (0)
#define PSTAGE_B(k0v, dst) do { \
    gload_lds16(Bbn + (size_t)drow * Kp + (k0v) + csw,        (dst) + ldst); \
    gload_lds16(Bbn + (size_t)(drow + 64) * Kp + (k0v) + csw, (dst) + 4096 + ldst); \
  } while (0)

    int k0off = ((quad       ^ (lrow & 7)) << 3);
    int k1off = (((4 + quad) ^ (lrow & 7)) << 3);

    short8 af0[4], af1[4], bf0[4], bf1[4];
    floatx4 acc[4][4];
    #pragma unroll
    for (int m = 0; m < 4; ++m)
        #pragma unroll
        for (int n = 0; n < 4; ++n)
            acc[m][n] = (floatx4){0.f, 0.f, 0.f, 0.f};

    // read one kk-cluster (8 x ds_read_b128): af rows awm+[0,64), bf rows bwn+[0,64)
#define PREAD(bufA, bufB, dA, dB, koff) do { \
    _Pragma("unroll") \
    for (int m = 0; m < 4; ++m) \
      dA[m] = *(const short8*)((bufA) + (awm + m * 16 + lrow) * 64 + (koff)); \
    _Pragma("unroll") \
    for (int n = 0; n < 4; ++n) \
      dB[n] = *(const short8*)((bufB) + (bwn + n * 16 + lrow) * 64 + (koff)); \
  } while (0)

#define PMFMA(fa, fb) do { \
    __builtin_amdgcn_s_setprio(1); \
    _Pragma("unroll") \
    for (int m = 0; m < 4; ++m) \
      _Pragma("unroll") \
      for (int n = 0; n < 4; ++n) \
        acc[m][n] = __builtin_amdgcn_mfma_f32_16x16x32_bf16(fa[m], fb[n], acc[m][n], 0, 0, 0); \
    __builtin_amdgcn_s_setprio(0); \
  } while (0)

    __hip_bfloat16 *aC = &As[0][0], *aN = &As[1][0], *aS = &As[2][0];
    __hip_bfloat16 *bC = &Bs[0][0], *bN = &Bs[1][0], *bS = &Bs[2][0];

    int NT = Kp >> 6;

    // prologue: stage t0 (6 loads) + t1 (6); GATE(6) -> t0 landed, t1 in flight
    PSTAGE_A(0, aC);  PSTAGE_B(0, bC);
    PSTAGE_A(64, aN); PSTAGE_B(64, bN);
    GATEP(6); SCBP(); BARP(); SCBP();
    PREAD(aC, bC, af0, bf0, k0off);            // kk0 of tile 0

    #pragma unroll 1
    for (int t = 0; t < NT; ++t) {
        int ks = ((t + 2 < NT) ? t + 2 : NT - 1) << 6;  // tail clamp: staged, never read
        // phase 0: stage t+2 -> spare buffer; read-ahead kk1(t); MFMA kk0(t)
        PSTAGE_A(ks, aS); PSTAGE_B(ks, bS);
        PREAD(aC, bC, af1, bf1, k1off);
        PMFMA(af0, bf0);
        // phase 1: gate t+1 landed; read-ahead kk0(t+1); MFMA kk1(t)
        GATEP(6); SCBP(); BARP(); SCBP();
        PREAD(aN, bN, af0, bf0, k0off);
        PMFMA(af1, bf1);
        SCBP(); BARP(); SCBP();
        // rotate buffers
        __hip_bfloat16* ta = aC; aC = aN; aN = aS; aS = ta;
        __hip_bfloat16* tb = bC; bC = bN; bN = bS; bS = tb;
    }
    asm volatile("s_waitcnt vmcnt(0)" ::: "memory");

    int cq4 = quad * 4;
    #pragma unroll
    for (int m = 0; m < 4; ++m) {
        int rowg = bm + awm + m * 16 + cq4;
        #pragma unroll
        for (int n = 0; n < 4; ++n) {
            int col = bn + bwn + n * 16 + lrow;
            #pragma unroll
            for (int r = 0; r < 4; ++r) {
                float v = acc[m][n][r];
                size_t idx = (size_t)(rowg + r) * ldc + col;
                if (EPI == 1) v += resid[idx];
                if (EPI == 2) { v += bias[col]; v = fast_gelu(v); }
                if (EPI == 3) { v += bias[col]; v += ((const float*)C)[idx]; }
                C[idx] = (CT)v;
            }
        }
    }
#undef PSTAGE_A
#undef PSTAGE_B
#undef PREAD
#undef PMFMA
}

// ---------------- RoPE ----------------
__global__ __launch_bounds__(256) void rope_q_kernel(float* __restrict__ Q)
{
    int idx = blockIdx.x * 256 + threadIdx.x;        // T*H*32
    int i = idx & 31;
    int h = (idx >> 5) & (H_ - 1);
    int t = idx >> 9;
    float f = expf(-(float)i * (9.210340371976184f / 64.0f));
    float ang = (float)(t & (S_ - 1)) * f;
    float sv, cv; sincosf(ang, &sv, &cv);
    float* p = Q + (size_t)t * D_ + h * DH_ + ND_;
    float u = p[i], v = p[i + 32];
    p[i]      = u * cv - v * sv;
    p[i + 32] = v * cv + u * sv;
}

__global__ __launch_bounds__(256) void rope_kr_bf(const float* __restrict__ ckv, __hip_bfloat16* __restrict__ kr)
{
    int idx = blockIdx.x * 256 + threadIdx.x;        // T*32
    int i = idx & 31;
    int t = idx >> 5;
    float f = expf(-(float)i * (9.210340371976184f / 64.0f));
    float ang = (float)(t & (S_ - 1)) * f;
    float sv, cv; sincosf(ang, &sv, &cv);
    const float* src = ckv + (size_t)t * CKW_ + KVP_;
    float u = src[i], v = src[i + 32];
    kr[(size_t)t * RD_ + i]      = __float2bfloat16(u * cv - v * sv);
    kr[(size_t)t * RD_ + i + 32] = __float2bfloat16(v * cv + u * sv);
}

// ---------------- V transpose: kvu[t][h*192+64+v] -> Vt[b*H+h][v][t] (bf16) ----------------
__global__ __launch_bounds__(256) void vt_pack(const __hip_bfloat16* __restrict__ kvu,
                                               __hip_bfloat16* __restrict__ Vt)
{
    int bh = blockIdx.y; int b = bh >> 4, h = bh & 15;
    int v = threadIdx.x & 127;
    int tg = blockIdx.x * 2 + (threadIdx.x >> 7);
    int t0 = tg * 8;
    short8 o;
    #pragma unroll
    for (int j = 0; j < 8; ++j) {
        __hip_bfloat16 e = kvu[(size_t)(b * S_ + t0 + j) * KVW_ + h * 192 + 64 + v];
        o[j] = *reinterpret_cast<short*>(&e);
    }
    *(short8*)&Vt[((size_t)bh * 128 + v) * S_ + t0] = o;
}

// ---------------- Flash MFMA attention (+ XCD chunk swizzle: same bh -> same XCD) ----
__global__ __launch_bounds__(256) void attn_mfma(const float* __restrict__ Q,
                                                 const __hip_bfloat16* __restrict__ KVU,
                                                 const __hip_bfloat16* __restrict__ KR,
                                                 const __hip_bfloat16* __restrict__ VT,
                                                 __hip_bfloat16* __restrict__ O)
{
    __shared__ __hip_bfloat16 Kls[64 * 64];
    __shared__ __hip_bfloat16 Krls[64 * 64];
    __shared__ __hip_bfloat16 Vls[128 * 64];
    __shared__ __hip_bfloat16 Pls[4 * 32 * 64];

    int tid = threadIdx.x, wid = tid >> 6, lane = tid & 63;
    int lrow = lane & 15, quad = lane >> 4;
    int kq8 = quad * 8;
    int o = blockIdx.y * 16 + blockIdx.x;
    int sId = (o & 7) * 64 + (o >> 3);
    int qtile = 15 - (sId & 15);
    int bh = sId >> 4;
    int b = bh >> 4, h = bh & 15;
    int q0 = qtile * 128, wq = wid * 32;

    const float scale = 0.08838834764831845f;

    short8 bq[2][2], bqr[2][2];
    #pragma unroll
    for (int n = 0; n < 2; ++n) {
        const float* qrow = Q + (size_t)(b * S_ + q0 + wq + n * 16 + lrow) * D_ + h * DH_;
        #pragma unroll
        for (int s = 0; s < 2; ++s) {
            int base = s * 32 + kq8;
            #pragma unroll
            for (int j = 0; j < 8; ++j) {
                bq[n][s][j]  = f2bs(qrow[base + j] * scale);
                bqr[n][s][j] = f2bs(qrow[64 + base + j] * scale);
            }
        }
    }

    float mstate[2] = {-INFINITY, -INFINITY};
    float lstate[2] = {0.f, 0.f};
    floatx4 acco[8][2];
    #pragma unroll
    for (int vt = 0; vt < 8; ++vt)
        #pragma unroll
        for (int n = 0; n < 2; ++n)
            acco[vt][n] = (floatx4){0.f, 0.f, 0.f, 0.f};

    int nk = qtile * 2 + 2;
    int qmax_w = q0 + wq + 31;

    for (int kt = 0; kt < nk; ++kt) {
        int k0 = kt * 64;
        #pragma unroll
        for (int it = 0; it < 2; ++it) {
            int c = it * 256 + tid;
            int row = c >> 3, g = c & 7;
            int col = ((g ^ (row & 7)) << 3);
            gload_lds16(KVU + (size_t)(b * S_ + k0 + row) * KVW_ + h * 192 + col, &Kls[c * 8]);
            gload_lds16(KR + (size_t)(b * S_ + k0 + row) * RD_ + col, &Krls[c * 8]);
        }
        #pragma unroll
        for (int it = 0; it < 4; ++it) {
            int c = it * 256 + tid;
            int row = c >> 3, g = c & 7;
            int col = ((g ^ (row & 7)) << 3);
            gload_lds16(VT + ((size_t)bh * 128 + row) * S_ + k0 + col, &Vls[c * 8]);
        }
        __syncthreads();

        if (k0 <= qmax_w) {
            floatx4 sacc[4][2];
            #pragma unroll
            for (int m = 0; m < 4; ++m)
                #pragma unroll
                for (int n = 0; n < 2; ++n)
                    sacc[m][n] = (floatx4){0.f, 0.f, 0.f, 0.f};
            #pragma unroll
            for (int m = 0; m < 4; ++m) {
                short8 ak[2], akr[2];
                #pragma unroll
                for (int s = 0; s < 2; ++s) {
                    ak[s]  = *(const short8*)&Kls[sw(m * 16 + lrow, s * 4 + quad)];
                    akr[s] = *(const short8*)&Krls[sw(m * 16 + lrow, s * 4 + quad)];
                }
                #pragma unroll
                for (int n = 0; n < 2; ++n)
                    #pragma unroll
                    for (int s = 0; s < 2; ++s) {
                        sacc[m][n] = __builtin_amdgcn_mfma_f32_16x16x32_bf16(ak[s],  bq[n][s],  sacc[m][n], 0, 0, 0);
                        sacc[m][n] = __builtin_amdgcn_mfma_f32_16x16x32_bf16(akr[s], bqr[n][s], sacc[m][n], 0, 0, 0);
                    }
            }
            #pragma unroll
            for (int n = 0; n < 2; ++n) {
                int qg = q0 + wq + n * 16 + lrow;
                float tmax = -INFINITY;
                #pragma unroll
                for (int m = 0; m < 4; ++m)
                    #pragma unroll
                    for (int r = 0; r < 4; ++r) {
                        int kg = k0 + m * 16 + quad * 4 + r;
                        if (kg > qg) sacc[m][n][r] = -1e30f;
                        tmax = fmaxf(tmax, sacc[m][n][r]);
                    }
                tmax = fmaxf(tmax, __shfl_xor(tmax, 16));
                tmax = fmaxf(tmax, __shfl_xor(tmax, 32));
                float mnew = fmaxf(mstate[n], tmax);
                float alpha = __expf(mstate[n] - mnew);
                mstate[n] = mnew;
                float ps = 0.f;
                #pragma unroll
                for (int m = 0; m < 4; ++m) {
                    sh4 pk;
                    #pragma unroll
                    for (int r = 0; r < 4; ++r) {
                        float p = __expf(sacc[m][n][r] - mnew);
                        ps += p;
                        pk[r] = f2bs(p);
                    }
                    int qloc = n * 16 + lrow;
                    int off = wid * 2048 + qloc * 64 + (((m * 2 + (quad >> 1)) ^ (lrow & 7)) << 3) + ((quad & 1) << 2);
                    *(sh4*)&Pls[off] = pk;
                }
                ps += __shfl_xor(ps, 16);
                ps += __shfl_xor(ps, 32);
                lstate[n] = lstate[n] * alpha + ps;
                #pragma unroll
                for (int vt = 0; vt < 8; ++vt)
                    #pragma unroll
                    for (int r = 0; r < 4; ++r)
                        acco[vt][n][r] *= alpha;
            }
            short8 bp[2][2];
            #pragma unroll
            for (int n = 0; n < 2; ++n)
                #pragma unroll
                for (int s = 0; s < 2; ++s)
                    bp[n][s] = *(const short8*)&Pls[wid * 2048 + sw(n * 16 + lrow, s * 4 + quad)];
            #pragma unroll
            for (int vt = 0; vt < 8; ++vt) {
                short8 av[2];
                #pragma unroll
                for (int s = 0; s < 2; ++s)
                    av[s] = *(const short8*)&Vls[sw(vt * 16 + lrow, s * 4 + quad)];
                #pragma unroll
                for (int n = 0; n < 2; ++n)
                    #pragma unroll
                    for (int s = 0; s < 2; ++s)
                        acco[vt][n] = __builtin_amdgcn_mfma_f32_16x16x32_bf16(av[s], bp[n][s], acco[vt][n], 0, 0, 0);
            }
        }
        __syncthreads();
    }

    #pragma unroll
    for (int n = 0; n < 2; ++n) {
        float inv = 1.0f / lstate[n];
        int tok = b * S_ + q0 + wq + n * 16 + lrow;
        #pragma unroll
        for (int vt = 0; vt < 8; ++vt) {
            sh4 o4;
            #pragma unroll
            for (int r = 0; r < 4; ++r) o4[r] = f2bs(acco[vt][n][r] * inv);
            *(sh4*)&O[(size_t)tok * D_ + h * DH_ + vt * 16 + quad * 4] = o4;
        }
    }
}

// ---------------- Launcher ----------------
extern "C" void kernel_launch(void* const* d_in, const int* in_sizes, int n_in,
                              void* d_out, int out_size, void* d_ws, size_t ws_size,
                              hipStream_t stream)
{
    const float* x     = (const float*)d_in[0];
    const float* anw   = (const float*)d_in[1];
    const float* anb   = (const float*)d_in[2];
    const float* W_dq  = (const float*)d_in[3];
    const float* qlw   = (const float*)d_in[4];
    const float* qlb   = (const float*)d_in[5];
    const float* W_uq  = (const float*)d_in[6];
    const float* W_dkv = (const float*)d_in[7];
    const float* kvlw  = (const float*)d_in[8];
    const float* kvlb  = (const float*)d_in[9];
    const float* W_ukv = (const float*)d_in[10];
    const float* W_o   = (const float*)d_in[11];
    const float* fnw   = (const float*)d_in[12];
    const float* fnb   = (const float*)d_in[13];
    const float* W1    = (const float*)d_in[14];
    const float* b1    = (const float*)d_in[15];
    const float* W2    = (const float*)d_in[16];
    const float* b2    = (const float*)d_in[17];

    float* out0 = (float*)d_out;                     // [T, D]
    float* ckv  = out0 + (size_t)T_ * D_;            // [T, 1429]

    float* ws = (float*)d_ws;
    float* Q  = ws;                                          // [T,2048] f32
    float* cq = Q + (size_t)T_ * D_;                         // [T,1024] f32
    __hip_bfloat16* kvu_bf = (__hip_bfloat16*)(cq + (size_t)T_ * QP_);  // [T,3072]
    __hip_bfloat16* kr_bf  = kvu_bf + (size_t)T_ * KVW_;     // [T,64]
    __hip_bfloat16* Vt     = kr_bf + (size_t)T_ * RD_;       // [B*H][128][S]
    __hip_bfloat16* h_bf   = Vt + (size_t)T_ * D_;           // [T,2048]
    __hip_bfloat16* cq_bf  = h_bf + (size_t)T_ * D_;         // [T,1024]
    __hip_bfloat16* kvl_bf = cq_bf + (size_t)T_ * QP_;       // [T,1408]
    __hip_bfloat16* o_bf   = kvl_bf + (size_t)T_ * KVP_PAD;  // [T,2048]
    __hip_bfloat16* wdq_t  = o_bf + (size_t)T_ * D_;         // [1024,2048]
    __hip_bfloat16* wuq_t  = wdq_t + (size_t)QP_ * D_;       // [2048,1024]
    __hip_bfloat16* wdkv_t = wuq_t + (size_t)D_ * QP_;       // [1536,2048]
    __hip_bfloat16* wukv_t = wdkv_t + (size_t)CKW_PAD * D_;  // [3072,1408]
    __hip_bfloat16* wo_b   = wukv_t + (size_t)KVW_ * KVP_PAD;// [2048,2048]
    __hip_bfloat16* w1_t   = wo_b + (size_t)D_ * D_;         // [8192,2048]
    __hip_bfloat16* w2_t   = w1_t + (size_t)FF_ * D_;        // [2048,8192]
    __hip_bfloat16* ff1_bf = (__hip_bfloat16*)ws;            // overlays Q+cq+kvu (dead by FFN)

    dim3 blk(256);
    dim3 blk8(512);

    { dim3 g(D_ / 32, QP_ / 32);       transpose_cvt<<<g, blk, 0, stream>>>(W_dq,  wdq_t,  D_, QP_, D_); }
    { dim3 g(QP_ / 32, D_ / 32);       transpose_cvt<<<g, blk, 0, stream>>>(W_uq,  wuq_t,  QP_, D_, QP_); }
    { dim3 g(D_ / 32, CKW_PAD / 32);   transpose_cvt<<<g, blk, 0, stream>>>(W_dkv, wdkv_t, D_, CKW_, D_); }
    { dim3 g(KVP_PAD / 32, KVW_ / 32); transpose_cvt<<<g, blk, 0, stream>>>(W_ukv, wukv_t, KVP_, KVW_, KVP_PAD); }
    { int n = D_ * D_;                 cvt_bf16<<<(n + 255) / 256, blk, 0, stream>>>(W_o, wo_b, n); }
    { dim3 g(D_ / 32, FF_ / 32);       transpose_cvt<<<g, blk, 0, stream>>>(W1, w1_t, D_, FF_, D_); }
    { dim3 g(FF_ / 32, D_ / 32);       transpose_cvt<<<g, blk, 0, stream>>>(W2, w2_t, FF_, D_, FF_); }

    ln_bf16<<<T_, blk, 0, stream>>>(x, D_, anw, anb, h_bf, D_, D_);
    { dim3 g(QP_ / 128, T_ / 128);   // 256 blocks at 128^2, full chip
      gemm_bf16<0, float><<<g, blk, 0, stream>>>(h_bf, wdq_t, cq, T_, QP_, D_, QP_, nullptr, nullptr); }
    ln_bf16<<<T_, blk, 0, stream>>>(cq, QP_, qlw, qlb, cq_bf, QP_, QP_);
    { dim3 g(D_ / 128, T_ / 256);    // 256 blocks
      gemm_pp<0, float><<<g, blk8, 0, stream>>>(cq_bf, wuq_t, Q, T_, D_, QP_, D_, nullptr, nullptr); }
    rope_q_kernel<<<(T_ * H_ * 32) / 256, blk, 0, stream>>>(Q);
    { dim3 g(CKW_PAD / 128, T_ / 128);  // 384 blocks at 128^2
      gemm_bf16<0, float><<<g, blk, 0, stream>>>(h_bf, wdkv_t, ckv, T_, CKW_, D_, CKW_, nullptr, nullptr); }
    ln_bf16<<<T_, blk, 0, stream>>>(ckv, CKW_, kvlw, kvlb, kvl_bf, KVP_PAD, KVP_);
    { dim3 g(KVW_ / 128, T_ / 256);  // 384 blocks
      gemm_pp<0, __hip_bfloat16><<<g, blk8, 0, stream>>>(kvl_bf, wukv_t, kvu_bf, T_, KVW_, KVP_PAD, KVW_, nullptr, nullptr); }
    rope_kr_bf<<<(T_ * 32) / 256, blk, 0, stream>>>(ckv, kr_bf);
    { dim3 g(S_ / 16, B_ * H_);
      vt_pack<<<g, blk, 0, stream>>>(kvu_bf, Vt); }
    { dim3 g(16, B_ * H_);
      attn_mfma<<<g, blk, 0, stream>>>(Q, kvu_bf, kr_bf, Vt, o_bf); }
    { dim3 g(D_ / 128, T_ / 256);    // 256 blocks
      gemm_pp<1, float><<<g, blk8, 0, stream>>>(o_bf, wo_b, out0, T_, D_, D_, D_, nullptr, x); }
    ln_bf16<<<T_, blk, 0, stream>>>(out0, D_, fnw, fnb, h_bf, D_, D_);
    { dim3 g(FF_ / 128, T_ / 256);   // 1024 blocks
      gemm_pp<2, __hip_bfloat16><<<g, blk8, 0, stream>>>(h_bf, w1_t, ff1_bf, T_, FF_, D_, FF_, b1, nullptr); }
    { dim3 g(D_ / 128, T_ / 256);    // 256 blocks
      gemm_pp<3, float><<<g, blk8, 0, stream>>>(ff1_bf, w2_t, out0, T_, D_, FF_, D_, b2, nullptr); }
}